// Round 2
// baseline (912.587 us; speedup 1.0000x reference)
//
#include <hip/hip_runtime.h>
#include <math.h>

#define DIMC 256
#define NHEAD 4

typedef unsigned short bf16u;

__device__ __forceinline__ float bf2f(bf16u u) {
    union { float f; unsigned int i; } c; c.i = ((unsigned int)u) << 16; return c.f;
}
__device__ __forceinline__ bf16u f2bf(float f) {
    union { float f; unsigned int i; } c; c.f = f;
    unsigned int r = c.i + 0x7fffu + ((c.i >> 16) & 1u);
    return (bf16u)(r >> 16);
}
__device__ __forceinline__ float4 load_bf4(const bf16u* p) {
    ushort4 raw = *(const ushort4*)p;
    return make_float4(bf2f(raw.x), bf2f(raw.y), bf2f(raw.z), bf2f(raw.w));
}
__device__ __forceinline__ void store_bf4(bf16u* p, float4 v) {
    ushort4 raw;
    raw.x = f2bf(v.x); raw.y = f2bf(v.y); raw.z = f2bf(v.z); raw.w = f2bf(v.w);
    *(ushort4*)p = raw;
}

// ---------------- graph preprocessing: CSR by dst ----------------

__global__ void count_kernel(const int* __restrict__ dst, int* __restrict__ count, int E) {
    int e = blockIdx.x * 256 + threadIdx.x;
    if (e < E) atomicAdd(&count[dst[e]], 1);
}

__global__ __launch_bounds__(1024) void scan_kernel(const int* __restrict__ count,
                                                    int* __restrict__ offsets,
                                                    float* __restrict__ dinv, int n) {
    __shared__ int part[1024];
    int t = threadIdx.x;
    int CH = (n + 1023) >> 10;
    int base = t * CH;
    int s = 0;
    for (int i = 0; i < CH; ++i) { int idx = base + i; if (idx < n) s += count[idx]; }
    part[t] = s;
    __syncthreads();
    for (int off = 1; off < 1024; off <<= 1) {
        int v = (t >= off) ? part[t - off] : 0;
        __syncthreads();
        part[t] += v;
        __syncthreads();
    }
    int run = part[t] - s;  // exclusive base of this chunk
    for (int i = 0; i < CH; ++i) {
        int idx = base + i;
        if (idx < n) {
            offsets[idx] = run;
            int c = count[idx];
            run += c;
            dinv[idx] = rsqrtf((float)(c + 1));  // +1 self loop, always > 0
        }
    }
}

__global__ void fill_kernel(const int* __restrict__ src, const int* __restrict__ dst,
                            const int* __restrict__ offsets, int* __restrict__ cursor,
                            int* __restrict__ srcs, int E) {
    int e = blockIdx.x * 256 + threadIdx.x;
    if (e < E) {
        int d = dst[e];
        int pos = atomicAdd(&cursor[d], 1);
        srcs[offsets[d] + pos] = src[e];
    }
}

// ---------------- SGEMM: C_bf16[M,256] = A_f32[M,256] @ W_f32[256, ldw](cols pre-offset) + bias ----
// BM=64, BN=64, BK=16, 256 threads, 4x4 per thread. Output width fixed 256 (grid.x = 4).

__global__ __launch_bounds__(256) void sgemm_f32A(const float* __restrict__ A,
                                                  const float* __restrict__ W, int ldw,
                                                  const float* __restrict__ bias,
                                                  bf16u* __restrict__ C, int M) {
    __shared__ float As[16][64];
    __shared__ float Bs[16][64];
    int bm = blockIdx.y * 64;
    int bn = blockIdx.x * 64;
    int t = threadIdx.x;
    int tm = t >> 4, tn = t & 15;
    int am = t >> 2, ks = (t & 3) * 4;   // A staging: row am, k-quad ks
    int kb = t >> 4, nb = (t & 15) * 4;  // B staging: k row kb, col-quad nb
    float c[4][4] = {};
    for (int k0 = 0; k0 < 256; k0 += 16) {
        float4 av = make_float4(0.f, 0.f, 0.f, 0.f);
        int gm = bm + am;
        if (gm < M) av = *(const float4*)(A + (size_t)gm * 256 + k0 + ks);
        As[ks + 0][am] = av.x; As[ks + 1][am] = av.y;
        As[ks + 2][am] = av.z; As[ks + 3][am] = av.w;
        *(float4*)&Bs[kb][nb] = *(const float4*)(W + (size_t)(k0 + kb) * ldw + bn + nb);
        __syncthreads();
#pragma unroll
        for (int kk = 0; kk < 16; ++kk) {
            float4 a4 = *(float4*)&As[kk][tm * 4];
            float4 b4 = *(float4*)&Bs[kk][tn * 4];
            float ar[4] = {a4.x, a4.y, a4.z, a4.w};
            float br[4] = {b4.x, b4.y, b4.z, b4.w};
#pragma unroll
            for (int i = 0; i < 4; ++i)
#pragma unroll
                for (int j = 0; j < 4; ++j) c[i][j] += ar[i] * br[j];
        }
        __syncthreads();
    }
    float bv[4] = {0.f, 0.f, 0.f, 0.f};
    if (bias) {
        float4 b4 = *(const float4*)(bias + bn + tn * 4);
        bv[0] = b4.x; bv[1] = b4.y; bv[2] = b4.z; bv[3] = b4.w;
    }
#pragma unroll
    for (int i = 0; i < 4; ++i) {
        int row = bm + tm * 4 + i;
        if (row < M) {
            float4 o = make_float4(c[i][0] + bv[0], c[i][1] + bv[1],
                                   c[i][2] + bv[2], c[i][3] + bv[3]);
            store_bf4(C + (size_t)row * 256 + bn + tn * 4, o);
        }
    }
}

// ---------------- final conv GEMM: out_f32[c*Nn+n] = W_cnn[c,:] @ tf_bf16[n,:] + b[c] ----------

__global__ __launch_bounds__(256) void sgemm_cnn(const float* __restrict__ Wc,
                                                 const bf16u* __restrict__ tf,
                                                 const float* __restrict__ bias,
                                                 float* __restrict__ out, int Nn) {
    __shared__ float As[16][64];
    __shared__ float Bs[16][64];
    int bm = blockIdx.y * 64;  // over c (256, exact)
    int bn = blockIdx.x * 64;  // over n (ragged)
    int t = threadIdx.x;
    int tm = t >> 4, tn = t & 15;
    int am = t >> 2, ks = (t & 3) * 4;
    float c[4][4] = {};
    for (int k0 = 0; k0 < 256; k0 += 16) {
        float4 av = *(const float4*)(Wc + (size_t)(bm + am) * 256 + k0 + ks);
        As[ks + 0][am] = av.x; As[ks + 1][am] = av.y;
        As[ks + 2][am] = av.z; As[ks + 3][am] = av.w;
        float4 bvv = make_float4(0.f, 0.f, 0.f, 0.f);
        int gn = bn + am;
        if (gn < Nn) bvv = load_bf4(tf + (size_t)gn * 256 + k0 + ks);
        Bs[ks + 0][am] = bvv.x; Bs[ks + 1][am] = bvv.y;
        Bs[ks + 2][am] = bvv.z; Bs[ks + 3][am] = bvv.w;
        __syncthreads();
#pragma unroll
        for (int kk = 0; kk < 16; ++kk) {
            float4 a4 = *(float4*)&As[kk][tm * 4];
            float4 b4 = *(float4*)&Bs[kk][tn * 4];
            float ar[4] = {a4.x, a4.y, a4.z, a4.w};
            float br[4] = {b4.x, b4.y, b4.z, b4.w};
#pragma unroll
            for (int i = 0; i < 4; ++i)
#pragma unroll
                for (int j = 0; j < 4; ++j) c[i][j] += ar[i] * br[j];
        }
        __syncthreads();
    }
#pragma unroll
    for (int i = 0; i < 4; ++i) {
        int row = bm + tm * 4 + i;  // c index < 256 always
        int n0 = bn + tn * 4;
        float bb = bias[row];
        if (n0 + 3 < Nn) {
            float4 o = make_float4(c[i][0] + bb, c[i][1] + bb, c[i][2] + bb, c[i][3] + bb);
            *(float4*)(out + (size_t)row * Nn + n0) = o;
        } else {
#pragma unroll
            for (int j = 0; j < 4; ++j)
                if (n0 + j < Nn) out[(size_t)row * Nn + n0 + j] = c[i][j] + bb;
        }
    }
}

// ---------------- GCN aggregation (gather-side, no atomics) ----------------

__global__ __launch_bounds__(256) void gcn_agg_kernel(const bf16u* __restrict__ h,
                                                      const float* __restrict__ dinv,
                                                      const int* __restrict__ offsets,
                                                      const int* __restrict__ count,
                                                      const int* __restrict__ srcs,
                                                      const float* __restrict__ b_gcn,
                                                      float* __restrict__ x) {
    int n = blockIdx.x;
    int c = threadIdx.x;
    float dn = dinv[n];
    float hn = bf2f(h[(size_t)n * DIMC + c]);
    int off = offsets[n], cnt = count[n];
    float acc = 0.f;
    for (int i = 0; i < cnt; ++i) {
        int s = srcs[off + i];
        acc += bf2f(h[(size_t)s * DIMC + c]) * dinv[s];
    }
    float val = dn * acc + hn * dn * dn + b_gcn[c];
    x[(size_t)n * DIMC + c] = fmaxf(val, 0.f);
}

// ---------------- per-head attention: online softmax, accumulate 0.25*head into outacc ------
// Block = 256 threads = 4 waves = 4 nodes; lane l holds channels 4l..4l+3 of this head.

__global__ __launch_bounds__(256) void attn_head_kernel(const bf16u* __restrict__ qh,
                                                        const bf16u* __restrict__ kh,
                                                        const bf16u* __restrict__ vh,
                                                        const int* __restrict__ offsets,
                                                        const int* __restrict__ count,
                                                        const int* __restrict__ srcs,
                                                        float* __restrict__ outacc, int N) {
    int n = blockIdx.x * 4 + (threadIdx.x >> 6);
    if (n >= N) return;
    int lane = threadIdx.x & 63;
    int cb = lane * 4;
    const float scale = 0.0625f;  // 1/sqrt(256)

    float4 qf = load_bf4(qh + (size_t)n * DIMC + cb);
    qf.x *= scale; qf.y *= scale; qf.z *= scale; qf.w *= scale;

    int off = offsets[n], cnt = count[n];
    float m = -INFINITY, denom = 0.f;
    float4 acc = make_float4(0.f, 0.f, 0.f, 0.f);
    for (int i = 0; i < cnt; ++i) {
        int s = srcs[off + i];
        float4 kf = load_bf4(kh + (size_t)s * DIMC + cb);
        float d = qf.x * kf.x + qf.y * kf.y + qf.z * kf.z + qf.w * kf.w;
#pragma unroll
        for (int msk = 32; msk >= 1; msk >>= 1) d += __shfl_xor(d, msk, 64);
        float4 vf = load_bf4(vh + (size_t)s * DIMC + cb);
        float nm = fmaxf(m, d);
        float so = __expf(m - nm);   // 0 on first edge (m = -inf)
        float p = __expf(d - nm);
        denom = denom * so + p;
        acc.x = acc.x * so + p * vf.x;
        acc.y = acc.y * so + p * vf.y;
        acc.z = acc.z * so + p * vf.z;
        acc.w = acc.w * so + p * vf.w;
        m = nm;
    }
    float inv = 0.25f / fmaxf(denom, 1e-16f);  // 0.25 = head mean
    float* o = outacc + (size_t)n * DIMC + cb;
    float4 cur = *(float4*)o;
    cur.x += acc.x * inv; cur.y += acc.y * inv;
    cur.z += acc.z * inv; cur.w += acc.w * inv;
    *(float4*)o = cur;
}

// ---------------- beta gate: tf = relu(beta*xr + (1-beta)*out) ----------------

__global__ __launch_bounds__(256) void gate_kernel(const float* __restrict__ outacc,
                                                   const bf16u* __restrict__ xr,
                                                   const float* __restrict__ W_beta,
                                                   bf16u* __restrict__ tf) {
    int n = blockIdx.x;
    int c = threadIdx.x;
    int lane = c & 63, w = c >> 6;
    float outc = outacc[(size_t)n * DIMC + c];
    float xrc = bf2f(xr[(size_t)n * DIMC + c]);
    float contrib = outc * W_beta[c] + xrc * W_beta[DIMC + c] + (outc - xrc) * W_beta[2 * DIMC + c];
#pragma unroll
    for (int msk = 32; msk >= 1; msk >>= 1) contrib += __shfl_xor(contrib, msk, 64);
    __shared__ float red[NHEAD];
    if (lane == 0) red[w] = contrib;
    __syncthreads();
    float ssum = red[0] + red[1] + red[2] + red[3];
    float beta = 1.0f / (1.0f + __expf(-ssum));
    float tv = beta * xrc + (1.0f - beta) * outc;
    tf[(size_t)n * DIMC + c] = f2bf(fmaxf(tv, 0.f));
}

// ---------------- launch ----------------

static inline size_t align_up(size_t x) { return (x + 255) & ~(size_t)255; }

extern "C" void kernel_launch(void* const* d_in, const int* in_sizes, int n_in,
                              void* d_out, int out_size, void* d_ws, size_t ws_size,
                              hipStream_t stream) {
    const float* f_all  = (const float*)d_in[0];
    const int*   eidx   = (const int*)d_in[1];
    const float* W_gcn  = (const float*)d_in[2];
    const float* b_gcn  = (const float*)d_in[3];
    const float* W_q    = (const float*)d_in[4];
    const float* b_q    = (const float*)d_in[5];
    const float* W_k    = (const float*)d_in[6];
    const float* b_k    = (const float*)d_in[7];
    const float* W_v    = (const float*)d_in[8];
    const float* b_v    = (const float*)d_in[9];
    const float* W_skip = (const float*)d_in[10];
    const float* b_skip = (const float*)d_in[11];
    const float* W_beta = (const float*)d_in[12];
    const float* W_cnn  = (const float*)d_in[13];
    const float* b_cnn  = (const float*)d_in[14];

    const int N = in_sizes[0] / DIMC;
    const int E = in_sizes[1] / 2;
    const int* src = eidx;
    const int* dst = eidx + E;

    // workspace layout (~93 MB total for N=20000, E=100000)
    char* p = (char*)d_ws;
    auto alloc = [&](size_t bytes) { char* r = p; p += align_up(bytes); return r; };
    int*   count   = (int*)alloc((size_t)N * 4);
    int*   cursor  = (int*)alloc((size_t)N * 4);
    int*   offsets = (int*)alloc((size_t)N * 4);
    int*   srcs    = (int*)alloc((size_t)E * 4);
    float* dinv    = (float*)alloc((size_t)N * 4);
    bf16u* h       = (bf16u*)alloc((size_t)N * DIMC * 2);   // reused as tf after gcn_agg
    float* x       = (float*)alloc((size_t)N * DIMC * 4);
    bf16u* xr      = (bf16u*)alloc((size_t)N * DIMC * 2);
    bf16u* qh      = (bf16u*)alloc((size_t)N * DIMC * 2);
    bf16u* kh      = (bf16u*)alloc((size_t)N * DIMC * 2);
    bf16u* vh      = (bf16u*)alloc((size_t)N * DIMC * 2);
    float* outacc  = (float*)alloc((size_t)N * DIMC * 4);
    bf16u* tf      = h;  // h is dead after gcn_agg

    hipMemsetAsync(count, 0, (size_t)N * 4, stream);
    hipMemsetAsync(cursor, 0, (size_t)N * 4, stream);
    hipMemsetAsync(outacc, 0, (size_t)N * DIMC * 4, stream);

    int eblocks = (E + 255) / 256;
    count_kernel<<<eblocks, 256, 0, stream>>>(dst, count, E);
    scan_kernel<<<1, 1024, 0, stream>>>(count, offsets, dinv, N);
    fill_kernel<<<eblocks, 256, 0, stream>>>(src, dst, offsets, cursor, srcs, E);

    dim3 ggrid(4, (N + 63) / 64);
    // h = bf16(f_all @ W_gcn)
    sgemm_f32A<<<ggrid, 256, 0, stream>>>(f_all, W_gcn, DIMC, nullptr, h, N);
    // x = relu(GCN-agg + b_gcn)  (f32)
    gcn_agg_kernel<<<N, 256, 0, stream>>>(h, dinv, offsets, count, srcs, b_gcn, x);
    // per-head q/k/v + attention, accumulating into outacc
    for (int hd = 0; hd < NHEAD; ++hd) {
        sgemm_f32A<<<ggrid, 256, 0, stream>>>(x, W_q + hd * DIMC, NHEAD * DIMC, b_q + hd * DIMC, qh, N);
        sgemm_f32A<<<ggrid, 256, 0, stream>>>(x, W_k + hd * DIMC, NHEAD * DIMC, b_k + hd * DIMC, kh, N);
        sgemm_f32A<<<ggrid, 256, 0, stream>>>(x, W_v + hd * DIMC, NHEAD * DIMC, b_v + hd * DIMC, vh, N);
        attn_head_kernel<<<(N + 3) / 4, 256, 0, stream>>>(qh, kh, vh, offsets, count, srcs, outacc, N);
    }
    // skip branch
    sgemm_f32A<<<ggrid, 256, 0, stream>>>(x, W_skip, DIMC, b_skip, xr, N);
    // beta gate -> tf (bf16)
    gate_kernel<<<N, 256, 0, stream>>>(outacc, xr, W_beta, tf);
    // out[c*N+n] = W_cnn @ tf^T + b_cnn
    sgemm_cnn<<<dim3((N + 63) / 64, DIMC / 64), 256, 0, stream>>>(W_cnn, tf, b_cnn, (float*)d_out, N);
}

// Round 3
// 633.473 us; speedup vs baseline: 1.4406x; 1.4406x over previous
//
#include <hip/hip_runtime.h>
#include <math.h>

#define DIMC 256
#define NHEAD 4

typedef unsigned short bf16u;
typedef __attribute__((ext_vector_type(8))) short bf16x8;
typedef __attribute__((ext_vector_type(4))) float f32x4;

__device__ __forceinline__ float bf2f(bf16u u) {
    union { float f; unsigned int i; } c; c.i = ((unsigned int)u) << 16; return c.f;
}
__device__ __forceinline__ bf16u f2bf(float f) {
    union { float f; unsigned int i; } c; c.f = f;
    unsigned int r = c.i + 0x7fffu + ((c.i >> 16) & 1u);
    return (bf16u)(r >> 16);
}
__device__ __forceinline__ float4 load_bf4(const bf16u* p) {
    ushort4 raw = *(const ushort4*)p;
    return make_float4(bf2f(raw.x), bf2f(raw.y), bf2f(raw.z), bf2f(raw.w));
}
__device__ __forceinline__ void store_bf4(bf16u* p, float4 v) {
    ushort4 raw;
    raw.x = f2bf(v.x); raw.y = f2bf(v.y); raw.z = f2bf(v.z); raw.w = f2bf(v.w);
    *(ushort4*)p = raw;
}

// ---------------- graph preprocessing: CSR by dst ----------------

__global__ void count_kernel(const int* __restrict__ dst, int* __restrict__ count, int E) {
    int e = blockIdx.x * 256 + threadIdx.x;
    if (e < E) atomicAdd(&count[dst[e]], 1);
}

__global__ __launch_bounds__(1024) void scan_kernel(const int* __restrict__ count,
                                                    int* __restrict__ offsets,
                                                    float* __restrict__ dinv, int n) {
    __shared__ int part[1024];
    int t = threadIdx.x;
    int CH = (n + 1023) >> 10;
    int base = t * CH;
    int s = 0;
    for (int i = 0; i < CH; ++i) { int idx = base + i; if (idx < n) s += count[idx]; }
    part[t] = s;
    __syncthreads();
    for (int off = 1; off < 1024; off <<= 1) {
        int v = (t >= off) ? part[t - off] : 0;
        __syncthreads();
        part[t] += v;
        __syncthreads();
    }
    int run = part[t] - s;
    for (int i = 0; i < CH; ++i) {
        int idx = base + i;
        if (idx < n) {
            offsets[idx] = run;
            int c = count[idx];
            run += c;
            dinv[idx] = rsqrtf((float)(c + 1));
        }
    }
}

__global__ void fill_kernel(const int* __restrict__ src, const int* __restrict__ dst,
                            const int* __restrict__ offsets, int* __restrict__ cursor,
                            int* __restrict__ srcs, int E) {
    int e = blockIdx.x * 256 + threadIdx.x;
    if (e < E) {
        int d = dst[e];
        int pos = atomicAdd(&cursor[d], 1);
        srcs[offsets[d] + pos] = src[e];
    }
}

// ---------------- converts ----------------

__global__ void cvt_kernel(const float* __restrict__ in, bf16u* __restrict__ out, int n4) {
    int i = blockIdx.x * 256 + threadIdx.x;
    if (i < n4) { float4 v = *(const float4*)(in + (size_t)i * 4); store_bf4(out + (size_t)i * 4, v); }
}

// in[k][n] (k=0..255, n=0..Nc-1) -> out[n][k] bf16
__global__ void transpose_cvt_kernel(const float* __restrict__ in, bf16u* __restrict__ out, int Nc) {
    int n = blockIdx.x;
    int kk = threadIdx.x;
    out[(size_t)n * DIMC + kk] = f2bf(in[(size_t)kk * Nc + n]);
}

// ---------------- zero-LDS MFMA GEMM ----------------
// C[M x Nc] = A_bf16[M x 256] @ (BT_bf16[Nc x 256])^T + bias
// BM=32, BN=256; 256 threads = 4 waves; wave w: rows (w&1)*16, cols (w>>1)*128.
// Fragments loaded directly from global: A[m][k..k+8], BT[n][k..k+8] contiguous 16B.

__global__ __launch_bounds__(256) void gemm_bf16(const bf16u* __restrict__ A,
                                                 const bf16u* __restrict__ BT,
                                                 const float* __restrict__ bias,
                                                 bf16u* __restrict__ C,
                                                 int M, int Nc, int ldc) {
    int t = threadIdx.x;
    int w = t >> 6, lane = t & 63;
    int q = lane >> 4, r = lane & 15;
    int bm = blockIdx.y * 32 + (w & 1) * 16;
    int bn = blockIdx.x * 256 + (w >> 1) * 128;
    int mload = bm + r; if (mload > M - 1) mload = M - 1;
    const bf16u* ap = A + (size_t)mload * DIMC + q * 8;
    const bf16u* bp[8];
#pragma unroll
    for (int nt = 0; nt < 8; ++nt) {
        int n = bn + nt * 16 + r; if (n > Nc - 1) n = Nc - 1;
        bp[nt] = BT + (size_t)n * DIMC + q * 8;
    }
    f32x4 acc[8] = {};
#pragma unroll
    for (int k0 = 0; k0 < DIMC; k0 += 32) {
        bf16x8 af = *(const bf16x8*)(ap + k0);
#pragma unroll
        for (int nt = 0; nt < 8; ++nt) {
            bf16x8 bf = *(const bf16x8*)(bp[nt] + k0);
            acc[nt] = __builtin_amdgcn_mfma_f32_16x16x32_bf16(af, bf, acc[nt], 0, 0, 0);
        }
    }
#pragma unroll
    for (int nt = 0; nt < 8; ++nt) {
        int col = bn + nt * 16 + r;
        if (col >= Nc) continue;
        float bv = bias ? bias[col] : 0.0f;
#pragma unroll
        for (int rg = 0; rg < 4; ++rg) {
            int row = bm + q * 4 + rg;
            if (row < M) C[(size_t)row * ldc + col] = f2bf(acc[nt][rg] + bv);
        }
    }
}

// f32-out variant, bias indexed by ROW (for the conv: out[c*N+n], bias b_cnn[c])
__global__ __launch_bounds__(256) void gemm_f32_rowbias(const bf16u* __restrict__ A,
                                                        const bf16u* __restrict__ BT,
                                                        const float* __restrict__ bias,
                                                        float* __restrict__ C,
                                                        int M, int Nc, int ldc) {
    int t = threadIdx.x;
    int w = t >> 6, lane = t & 63;
    int q = lane >> 4, r = lane & 15;
    int bm = blockIdx.y * 32 + (w & 1) * 16;
    int bn = blockIdx.x * 256 + (w >> 1) * 128;
    int mload = bm + r; if (mload > M - 1) mload = M - 1;
    const bf16u* ap = A + (size_t)mload * DIMC + q * 8;
    const bf16u* bp[8];
#pragma unroll
    for (int nt = 0; nt < 8; ++nt) {
        int n = bn + nt * 16 + r; if (n > Nc - 1) n = Nc - 1;
        bp[nt] = BT + (size_t)n * DIMC + q * 8;
    }
    f32x4 acc[8] = {};
#pragma unroll
    for (int k0 = 0; k0 < DIMC; k0 += 32) {
        bf16x8 af = *(const bf16x8*)(ap + k0);
#pragma unroll
        for (int nt = 0; nt < 8; ++nt) {
            bf16x8 bf = *(const bf16x8*)(bp[nt] + k0);
            acc[nt] = __builtin_amdgcn_mfma_f32_16x16x32_bf16(af, bf, acc[nt], 0, 0, 0);
        }
    }
#pragma unroll
    for (int nt = 0; nt < 8; ++nt) {
        int col = bn + nt * 16 + r;
        if (col >= Nc) continue;
#pragma unroll
        for (int rg = 0; rg < 4; ++rg) {
            int row = bm + q * 4 + rg;
            if (row < M) C[(size_t)row * ldc + col] = acc[nt][rg] + bias[row];
        }
    }
}

// ---------------- GCN aggregation (gather-side, no atomics) ----------------

__global__ __launch_bounds__(256) void gcn_agg_kernel(const bf16u* __restrict__ h,
                                                      const float* __restrict__ dinv,
                                                      const int* __restrict__ offsets,
                                                      const int* __restrict__ count,
                                                      const int* __restrict__ srcs,
                                                      const float* __restrict__ b_gcn,
                                                      bf16u* __restrict__ x) {
    int n = blockIdx.x;
    int c = threadIdx.x;
    float dn = dinv[n];
    float hn = bf2f(h[(size_t)n * DIMC + c]);
    int off = offsets[n], cnt = count[n];
    float acc = 0.f;
    for (int i = 0; i < cnt; ++i) {
        int s = srcs[off + i];
        acc += bf2f(h[(size_t)s * DIMC + c]) * dinv[s];
    }
    float val = dn * acc + hn * dn * dn + b_gcn[c];
    x[(size_t)n * DIMC + c] = f2bf(fmaxf(val, 0.f));
}

// ---------------- FUSED transformer: all heads + online softmax + beta gate ----------------
// q/k/v are [N,1024] bf16. Block = 256 thr = 4 waves; wave = head; lane covers 4 channels.

__global__ __launch_bounds__(256) void transformer_kernel(const bf16u* __restrict__ q,
                                                          const bf16u* __restrict__ k,
                                                          const bf16u* __restrict__ v,
                                                          const bf16u* __restrict__ xr,
                                                          const float* __restrict__ W_beta,
                                                          const int* __restrict__ offsets,
                                                          const int* __restrict__ count,
                                                          const int* __restrict__ srcs,
                                                          bf16u* __restrict__ tf) {
    int n = blockIdx.x;
    int tid = threadIdx.x;
    int hd = tid >> 6;
    int lane = tid & 63;
    int cb = lane * 4;
    const float scale = 0.0625f;  // 1/sqrt(256)

    float4 qf = load_bf4(q + (size_t)n * 1024 + hd * DIMC + cb);
    qf.x *= scale; qf.y *= scale; qf.z *= scale; qf.w *= scale;

    int off = offsets[n], cnt = count[n];
    float m = -INFINITY, denom = 0.f;
    float4 acc = make_float4(0.f, 0.f, 0.f, 0.f);
    for (int i = 0; i < cnt; ++i) {
        int s = srcs[off + i];
        float4 kf = load_bf4(k + (size_t)s * 1024 + hd * DIMC + cb);
        float d = qf.x * kf.x + qf.y * kf.y + qf.z * kf.z + qf.w * kf.w;
#pragma unroll
        for (int msk = 32; msk >= 1; msk >>= 1) d += __shfl_xor(d, msk, 64);
        float4 vf = load_bf4(v + (size_t)s * 1024 + hd * DIMC + cb);
        float nm = fmaxf(m, d);
        float so = __expf(m - nm);
        float p = __expf(d - nm);
        denom = denom * so + p;
        acc.x = acc.x * so + p * vf.x;
        acc.y = acc.y * so + p * vf.y;
        acc.z = acc.z * so + p * vf.z;
        acc.w = acc.w * so + p * vf.w;
        m = nm;
    }
    float inv = 1.0f / fmaxf(denom, 1e-16f);

    __shared__ float lds_out[NHEAD][DIMC];
    lds_out[hd][cb + 0] = acc.x * inv;
    lds_out[hd][cb + 1] = acc.y * inv;
    lds_out[hd][cb + 2] = acc.z * inv;
    lds_out[hd][cb + 3] = acc.w * inv;
    __syncthreads();

    int c = tid;
    float outc = 0.25f * (lds_out[0][c] + lds_out[1][c] + lds_out[2][c] + lds_out[3][c]);
    float xrc = bf2f(xr[(size_t)n * DIMC + c]);
    float contrib = outc * W_beta[c] + xrc * W_beta[DIMC + c] + (outc - xrc) * W_beta[2 * DIMC + c];
#pragma unroll
    for (int msk = 32; msk >= 1; msk >>= 1) contrib += __shfl_xor(contrib, msk, 64);
    __shared__ float red[NHEAD];
    if (lane == 0) red[hd] = contrib;
    __syncthreads();
    float ssum = red[0] + red[1] + red[2] + red[3];
    float beta = 1.0f / (1.0f + __expf(-ssum));
    float tv = beta * xrc + (1.0f - beta) * outc;
    tf[(size_t)n * DIMC + c] = f2bf(fmaxf(tv, 0.f));
}

// ---------------- per-head fallback path (small workspace) ----------------

__global__ __launch_bounds__(256) void attn_head_kernel(const bf16u* __restrict__ qh,
                                                        const bf16u* __restrict__ kh,
                                                        const bf16u* __restrict__ vh,
                                                        const int* __restrict__ offsets,
                                                        const int* __restrict__ count,
                                                        const int* __restrict__ srcs,
                                                        float* __restrict__ outacc, int N) {
    int n = blockIdx.x * 4 + (threadIdx.x >> 6);
    if (n >= N) return;
    int lane = threadIdx.x & 63;
    int cb = lane * 4;
    const float scale = 0.0625f;

    float4 qf = load_bf4(qh + (size_t)n * DIMC + cb);
    qf.x *= scale; qf.y *= scale; qf.z *= scale; qf.w *= scale;

    int off = offsets[n], cnt = count[n];
    float m = -INFINITY, denom = 0.f;
    float4 acc = make_float4(0.f, 0.f, 0.f, 0.f);
    for (int i = 0; i < cnt; ++i) {
        int s = srcs[off + i];
        float4 kf = load_bf4(kh + (size_t)s * DIMC + cb);
        float d = qf.x * kf.x + qf.y * kf.y + qf.z * kf.z + qf.w * kf.w;
#pragma unroll
        for (int msk = 32; msk >= 1; msk >>= 1) d += __shfl_xor(d, msk, 64);
        float4 vf = load_bf4(vh + (size_t)s * DIMC + cb);
        float nm = fmaxf(m, d);
        float so = __expf(m - nm);
        float p = __expf(d - nm);
        denom = denom * so + p;
        acc.x = acc.x * so + p * vf.x;
        acc.y = acc.y * so + p * vf.y;
        acc.z = acc.z * so + p * vf.z;
        acc.w = acc.w * so + p * vf.w;
        m = nm;
    }
    float inv = 0.25f / fmaxf(denom, 1e-16f);
    float* o = outacc + (size_t)n * DIMC + cb;
    float4 cur = *(float4*)o;
    cur.x += acc.x * inv; cur.y += acc.y * inv;
    cur.z += acc.z * inv; cur.w += acc.w * inv;
    *(float4*)o = cur;
}

__global__ __launch_bounds__(256) void gate_kernel(const float* __restrict__ outacc,
                                                   const bf16u* __restrict__ xr,
                                                   const float* __restrict__ W_beta,
                                                   bf16u* __restrict__ tf) {
    int n = blockIdx.x;
    int c = threadIdx.x;
    int lane = c & 63, w = c >> 6;
    float outc = outacc[(size_t)n * DIMC + c];
    float xrc = bf2f(xr[(size_t)n * DIMC + c]);
    float contrib = outc * W_beta[c] + xrc * W_beta[DIMC + c] + (outc - xrc) * W_beta[2 * DIMC + c];
#pragma unroll
    for (int msk = 32; msk >= 1; msk >>= 1) contrib += __shfl_xor(contrib, msk, 64);
    __shared__ float red[NHEAD];
    if (lane == 0) red[w] = contrib;
    __syncthreads();
    float ssum = red[0] + red[1] + red[2] + red[3];
    float beta = 1.0f / (1.0f + __expf(-ssum));
    float tv = beta * xrc + (1.0f - beta) * outc;
    tf[(size_t)n * DIMC + c] = f2bf(fmaxf(tv, 0.f));
}

// ---------------- launch ----------------

static inline size_t align_up(size_t x) { return (x + 255) & ~(size_t)255; }

extern "C" void kernel_launch(void* const* d_in, const int* in_sizes, int n_in,
                              void* d_out, int out_size, void* d_ws, size_t ws_size,
                              hipStream_t stream) {
    const float* f_all  = (const float*)d_in[0];
    const int*   eidx   = (const int*)d_in[1];
    const float* W_gcn  = (const float*)d_in[2];
    const float* b_gcn  = (const float*)d_in[3];
    const float* W_q    = (const float*)d_in[4];
    const float* b_q    = (const float*)d_in[5];
    const float* W_k    = (const float*)d_in[6];
    const float* b_k    = (const float*)d_in[7];
    const float* W_v    = (const float*)d_in[8];
    const float* b_v    = (const float*)d_in[9];
    const float* W_skip = (const float*)d_in[10];
    const float* b_skip = (const float*)d_in[11];
    const float* W_beta = (const float*)d_in[12];
    const float* W_cnn  = (const float*)d_in[13];
    const float* b_cnn  = (const float*)d_in[14];

    const int N = in_sizes[0] / DIMC;
    const int E = in_sizes[1] / 2;
    const int* src = eidx;
    const int* dst = eidx + E;

    char* p = (char*)d_ws;
    auto alloc = [&](size_t bytes) { char* r = p; p += align_up(bytes); return r; };
    int*   count   = (int*)alloc((size_t)N * 4);
    int*   cursor  = (int*)alloc((size_t)N * 4);
    int*   offsets = (int*)alloc((size_t)N * 4);
    int*   srcs    = (int*)alloc((size_t)E * 4);
    float* dinv    = (float*)alloc((size_t)N * 4);
    bf16u* WgcnT   = (bf16u*)alloc(256 * 256 * 2);
    bf16u* WqT     = (bf16u*)alloc(1024 * 256 * 2);
    bf16u* WkT     = (bf16u*)alloc(1024 * 256 * 2);
    bf16u* WvT     = (bf16u*)alloc(1024 * 256 * 2);
    bf16u* WskipT  = (bf16u*)alloc(256 * 256 * 2);
    bf16u* Wcnn_b  = (bf16u*)alloc(256 * 256 * 2);
    bf16u* xbuf    = (bf16u*)alloc((size_t)N * DIMC * 2);  // f_all bf16, then x
    bf16u* h       = (bf16u*)alloc((size_t)N * DIMC * 2);  // then tf
    bf16u* xr      = (bf16u*)alloc((size_t)N * DIMC * 2);

    size_t used = (size_t)(p - (char*)d_ws);
    size_t fused_need = used + 3 * align_up((size_t)N * 1024 * 2);
    bool fused = fused_need <= ws_size;

    hipMemsetAsync(count, 0, (size_t)N * 4, stream);
    hipMemsetAsync(cursor, 0, (size_t)N * 4, stream);

    int eblocks = (E + 255) / 256;
    count_kernel<<<eblocks, 256, 0, stream>>>(dst, count, E);
    scan_kernel<<<1, 1024, 0, stream>>>(count, offsets, dinv, N);
    fill_kernel<<<eblocks, 256, 0, stream>>>(src, dst, offsets, cursor, srcs, E);

    // weight preprocessing: transpose+convert to BT bf16 [Nc][256]
    cvt_kernel<<<((N * DIMC / 4) + 255) / 256, 256, 0, stream>>>(f_all, xbuf, N * DIMC / 4);
    transpose_cvt_kernel<<<256, 256, 0, stream>>>(W_gcn, WgcnT, 256);
    transpose_cvt_kernel<<<1024, 256, 0, stream>>>(W_q, WqT, 1024);
    transpose_cvt_kernel<<<1024, 256, 0, stream>>>(W_k, WkT, 1024);
    transpose_cvt_kernel<<<1024, 256, 0, stream>>>(W_v, WvT, 1024);
    transpose_cvt_kernel<<<256, 256, 0, stream>>>(W_skip, WskipT, 256);
    cvt_kernel<<<(256 * 256 / 4 + 255) / 256, 256, 0, stream>>>(W_cnn, Wcnn_b, 256 * 256 / 4);

    int mby = (N + 31) / 32;
    // h = bf16(f_all @ W_gcn)
    gemm_bf16<<<dim3(1, mby), 256, 0, stream>>>(xbuf, WgcnT, nullptr, h, N, 256, 256);
    // x = relu(GCN-agg + b_gcn)  (bf16, overwrites xbuf)
    gcn_agg_kernel<<<N, 256, 0, stream>>>(h, dinv, offsets, count, srcs, b_gcn, xbuf);

    if (fused) {
        bf16u* q = (bf16u*)alloc((size_t)N * 1024 * 2);
        bf16u* k = (bf16u*)alloc((size_t)N * 1024 * 2);
        bf16u* v = (bf16u*)alloc((size_t)N * 1024 * 2);
        gemm_bf16<<<dim3(4, mby), 256, 0, stream>>>(xbuf, WqT, b_q, q, N, 1024, 1024);
        gemm_bf16<<<dim3(4, mby), 256, 0, stream>>>(xbuf, WkT, b_k, k, N, 1024, 1024);
        gemm_bf16<<<dim3(4, mby), 256, 0, stream>>>(xbuf, WvT, b_v, v, N, 1024, 1024);
        gemm_bf16<<<dim3(1, mby), 256, 0, stream>>>(xbuf, WskipT, b_skip, xr, N, 256, 256);
        transformer_kernel<<<N, 256, 0, stream>>>(q, k, v, xr, W_beta, offsets, count, srcs, h);
    } else {
        bf16u* qh = (bf16u*)alloc((size_t)N * DIMC * 2);
        bf16u* kh = (bf16u*)alloc((size_t)N * DIMC * 2);
        bf16u* vh = (bf16u*)alloc((size_t)N * DIMC * 2);
        float* outacc = (float*)alloc((size_t)N * DIMC * 4);
        hipMemsetAsync(outacc, 0, (size_t)N * DIMC * 4, stream);
        for (int hd = 0; hd < NHEAD; ++hd) {
            gemm_bf16<<<dim3(1, mby), 256, 0, stream>>>(xbuf, WqT + hd * 256 * 256, b_q + hd * 256, qh, N, 256, 256);
            gemm_bf16<<<dim3(1, mby), 256, 0, stream>>>(xbuf, WkT + hd * 256 * 256, b_k + hd * 256, kh, N, 256, 256);
            gemm_bf16<<<dim3(1, mby), 256, 0, stream>>>(xbuf, WvT + hd * 256 * 256, b_v + hd * 256, vh, N, 256, 256);
            attn_head_kernel<<<(N + 3) / 4, 256, 0, stream>>>(qh, kh, vh, offsets, count, srcs, outacc, N);
        }
        gemm_bf16<<<dim3(1, mby), 256, 0, stream>>>(xbuf, WskipT, b_skip, xr, N, 256, 256);
        gate_kernel<<<N, 256, 0, stream>>>(outacc, xr, W_beta, h);
    }

    // out[c*N+n] = W_cnn @ tf^T + b_cnn   (tf lives in h)
    gemm_f32_rowbias<<<dim3((N + 255) / 256, (256 + 31) / 32), 256, 0, stream>>>(
        Wcnn_b, h, b_cnn, (float*)d_out, 256, N, N);
}

// Round 4
// 411.388 us; speedup vs baseline: 2.2183x; 1.5398x over previous
//
#include <hip/hip_runtime.h>
#include <math.h>

#define DIMC 256
#define NHEAD 4

typedef unsigned short bf16u;
typedef __attribute__((ext_vector_type(8))) short bf16x8;
typedef __attribute__((ext_vector_type(4))) float f32x4;

__device__ __forceinline__ float bf2f(bf16u u) {
    union { float f; unsigned int i; } c; c.i = ((unsigned int)u) << 16; return c.f;
}
__device__ __forceinline__ bf16u f2bf(float f) {
    union { float f; unsigned int i; } c; c.f = f;
    unsigned int r = c.i + 0x7fffu + ((c.i >> 16) & 1u);
    return (bf16u)(r >> 16);
}
__device__ __forceinline__ float4 load_bf4(const bf16u* p) {
    ushort4 raw = *(const ushort4*)p;
    return make_float4(bf2f(raw.x), bf2f(raw.y), bf2f(raw.z), bf2f(raw.w));
}
__device__ __forceinline__ void store_bf4(bf16u* p, float4 v) {
    ushort4 raw;
    raw.x = f2bf(v.x); raw.y = f2bf(v.y); raw.z = f2bf(v.z); raw.w = f2bf(v.w);
    *(ushort4*)p = raw;
}

// ---------------- graph preprocessing: CSR by dst ----------------

__global__ void count_kernel(const int* __restrict__ dst, int* __restrict__ count, int E) {
    int e = blockIdx.x * 256 + threadIdx.x;
    if (e < E) atomicAdd(&count[dst[e]], 1);
}

__global__ __launch_bounds__(1024) void scan_kernel(const int* __restrict__ count,
                                                    int* __restrict__ offsets,
                                                    float* __restrict__ dinv, int n) {
    __shared__ int part[1024];
    int t = threadIdx.x;
    int CH = (n + 1023) >> 10;
    int base = t * CH;
    int s = 0;
    for (int i = 0; i < CH; ++i) { int idx = base + i; if (idx < n) s += count[idx]; }
    part[t] = s;
    __syncthreads();
    for (int off = 1; off < 1024; off <<= 1) {
        int v = (t >= off) ? part[t - off] : 0;
        __syncthreads();
        part[t] += v;
        __syncthreads();
    }
    int run = part[t] - s;
    for (int i = 0; i < CH; ++i) {
        int idx = base + i;
        if (idx < n) {
            offsets[idx] = run;
            int c = count[idx];
            run += c;
            dinv[idx] = rsqrtf((float)(c + 1));
        }
    }
}

__global__ void fill_kernel(const int* __restrict__ src, const int* __restrict__ dst,
                            const int* __restrict__ offsets, int* __restrict__ cursor,
                            int* __restrict__ srcs, int E) {
    int e = blockIdx.x * 256 + threadIdx.x;
    if (e < E) {
        int d = dst[e];
        int pos = atomicAdd(&cursor[d], 1);
        srcs[offsets[d] + pos] = src[e];
    }
}

// ---------------- converts ----------------

__global__ void cvt_kernel(const float* __restrict__ in, bf16u* __restrict__ out, int n4) {
    int i = blockIdx.x * 256 + threadIdx.x;
    if (i < n4) { float4 v = *(const float4*)(in + (size_t)i * 4); store_bf4(out + (size_t)i * 4, v); }
}

// in[k][n] (k=0..255) -> out[n][k] bf16
__global__ void transpose_cvt_kernel(const float* __restrict__ in, bf16u* __restrict__ out, int Nc) {
    int n = blockIdx.x;
    int kk = threadIdx.x;
    out[(size_t)n * DIMC + kk] = f2bf(in[(size_t)kk * Nc + n]);
}

__global__ void concat_bias_kernel(const float* __restrict__ a, const float* __restrict__ b,
                                   const float* __restrict__ c, float* __restrict__ o) {
    int i = blockIdx.x * 256 + threadIdx.x;
    if (i < 3072) o[i] = (i < 1024) ? a[i] : (i < 2048 ? b[i - 1024] : c[i - 2048]);
}

// ---------------- LDS-staged MFMA GEMM (m93-style 128x128 tile, BK=32) ----------------
// C[M x Nc] = A_bf16[M x 256] @ (BT_bf16[Nc x 256])^T (+bias)
// 256 threads = 4 waves in 2x2; each wave 64x64 = 4x4 frags of 16x16x32.
// ROWBIAS=false: bf16 out, bias indexed by col. ROWBIAS=true: f32 out, bias by row.

template <bool ROWBIAS>
__global__ __launch_bounds__(256) void gemm_tile(const bf16u* __restrict__ A,
                                                 const bf16u* __restrict__ BT,
                                                 const float* __restrict__ bias,
                                                 void* __restrict__ Cout,
                                                 int M, int Nc, int ldc) {
    __shared__ bf16u As[128][40];  // +16B pad: frag ds_read_b128 2-way (free)
    __shared__ bf16u Bs[128][40];
    int t = threadIdx.x;
    int w = t >> 6, lane = t & 63;
    int q = lane >> 4, r = lane & 15;
    int wm = (w & 1) * 64, wn = (w >> 1) * 64;
    int bm = blockIdx.y * 128, bn = blockIdx.x * 128;

    // staging: thread t covers rows (t>>2) and (t>>2)+64, k-chunk (t&3)*8
    int srow = t >> 2, scol = (t & 3) * 8;
    int arow0 = bm + srow;      if (arow0 >= M)  arow0 = M - 1;
    int arow1 = bm + 64 + srow; if (arow1 >= M)  arow1 = M - 1;
    int brow0 = bn + srow;      if (brow0 >= Nc) brow0 = Nc - 1;
    int brow1 = bn + 64 + srow; if (brow1 >= Nc) brow1 = Nc - 1;
    const bf16u* a0 = A + (size_t)arow0 * DIMC + scol;
    const bf16u* a1 = A + (size_t)arow1 * DIMC + scol;
    const bf16u* b0 = BT + (size_t)brow0 * DIMC + scol;
    const bf16u* b1 = BT + (size_t)brow1 * DIMC + scol;

    f32x4 acc[4][4] = {};
    bf16x8 va0 = *(const bf16x8*)(a0);
    bf16x8 va1 = *(const bf16x8*)(a1);
    bf16x8 vb0 = *(const bf16x8*)(b0);
    bf16x8 vb1 = *(const bf16x8*)(b1);
    for (int k0 = 0; k0 < DIMC; k0 += 32) {
        __syncthreads();  // previous iter's frag reads complete
        *(bf16x8*)&As[srow][scol] = va0;
        *(bf16x8*)&As[64 + srow][scol] = va1;
        *(bf16x8*)&Bs[srow][scol] = vb0;
        *(bf16x8*)&Bs[64 + srow][scol] = vb1;
        __syncthreads();
        if (k0 + 32 < DIMC) {  // prefetch next tile while MFMAs run
            va0 = *(const bf16x8*)(a0 + k0 + 32);
            va1 = *(const bf16x8*)(a1 + k0 + 32);
            vb0 = *(const bf16x8*)(b0 + k0 + 32);
            vb1 = *(const bf16x8*)(b1 + k0 + 32);
        }
        bf16x8 af[4], bfr[4];
#pragma unroll
        for (int i = 0; i < 4; ++i) af[i] = *(const bf16x8*)&As[wm + i * 16 + r][q * 8];
#pragma unroll
        for (int j = 0; j < 4; ++j) bfr[j] = *(const bf16x8*)&Bs[wn + j * 16 + r][q * 8];
#pragma unroll
        for (int i = 0; i < 4; ++i)
#pragma unroll
            for (int j = 0; j < 4; ++j)
                acc[i][j] = __builtin_amdgcn_mfma_f32_16x16x32_bf16(af[i], bfr[j], acc[i][j], 0, 0, 0);
    }
#pragma unroll
    for (int j = 0; j < 4; ++j) {
        int col = bn + wn + j * 16 + r;
        if (col >= Nc) continue;
        float cb = (!ROWBIAS && bias) ? bias[col] : 0.0f;
#pragma unroll
        for (int i = 0; i < 4; ++i) {
#pragma unroll
            for (int rg = 0; rg < 4; ++rg) {
                int row = bm + wm + i * 16 + q * 4 + rg;
                if (row < M) {
                    if (ROWBIAS)
                        ((float*)Cout)[(size_t)row * ldc + col] = acc[i][j][rg] + bias[row];
                    else
                        ((bf16u*)Cout)[(size_t)row * ldc + col] = f2bf(acc[i][j][rg] + cb);
                }
            }
        }
    }
}

// ---------------- GCN aggregation (gather-side, no atomics) ----------------

__global__ __launch_bounds__(256) void gcn_agg_kernel(const bf16u* __restrict__ h,
                                                      const float* __restrict__ dinv,
                                                      const int* __restrict__ offsets,
                                                      const int* __restrict__ count,
                                                      const int* __restrict__ srcs,
                                                      const float* __restrict__ b_gcn,
                                                      bf16u* __restrict__ x) {
    int n = blockIdx.x;
    int c = threadIdx.x;
    float dn = dinv[n];
    float hn = bf2f(h[(size_t)n * DIMC + c]);
    int off = offsets[n], cnt = count[n];
    float acc = 0.f;
    for (int i = 0; i < cnt; ++i) {
        int s = srcs[off + i];
        acc += bf2f(h[(size_t)s * DIMC + c]) * dinv[s];
    }
    float val = dn * acc + hn * dn * dn + b_gcn[c];
    x[(size_t)n * DIMC + c] = f2bf(fmaxf(val, 0.f));
}

// ---------------- FUSED transformer: all heads + online softmax + beta gate ----------------
// q/k/v live in one qkv[N][stride] buffer (stride=3072): q at +0, k at +1024, v at +2048.

__global__ __launch_bounds__(256) void transformer_kernel(const bf16u* __restrict__ q,
                                                          const bf16u* __restrict__ k,
                                                          const bf16u* __restrict__ v,
                                                          int stride,
                                                          const bf16u* __restrict__ xr,
                                                          const float* __restrict__ W_beta,
                                                          const int* __restrict__ offsets,
                                                          const int* __restrict__ count,
                                                          const int* __restrict__ srcs,
                                                          bf16u* __restrict__ tf) {
    int n = blockIdx.x;
    int tid = threadIdx.x;
    int hd = tid >> 6;
    int lane = tid & 63;
    int cb = lane * 4;
    const float scale = 0.0625f;  // 1/sqrt(256)

    float4 qf = load_bf4(q + (size_t)n * stride + hd * DIMC + cb);
    qf.x *= scale; qf.y *= scale; qf.z *= scale; qf.w *= scale;

    int off = offsets[n], cnt = count[n];
    float m = -INFINITY, denom = 0.f;
    float4 acc = make_float4(0.f, 0.f, 0.f, 0.f);
    for (int i = 0; i < cnt; ++i) {
        int s = srcs[off + i];
        float4 kf = load_bf4(k + (size_t)s * stride + hd * DIMC + cb);
        float d = qf.x * kf.x + qf.y * kf.y + qf.z * kf.z + qf.w * kf.w;
#pragma unroll
        for (int msk = 32; msk >= 1; msk >>= 1) d += __shfl_xor(d, msk, 64);
        float4 vf = load_bf4(v + (size_t)s * stride + hd * DIMC + cb);
        float nm = fmaxf(m, d);
        float so = __expf(m - nm);
        float p = __expf(d - nm);
        denom = denom * so + p;
        acc.x = acc.x * so + p * vf.x;
        acc.y = acc.y * so + p * vf.y;
        acc.z = acc.z * so + p * vf.z;
        acc.w = acc.w * so + p * vf.w;
        m = nm;
    }
    float inv = 1.0f / fmaxf(denom, 1e-16f);

    __shared__ float lds_out[NHEAD][DIMC];
    lds_out[hd][cb + 0] = acc.x * inv;
    lds_out[hd][cb + 1] = acc.y * inv;
    lds_out[hd][cb + 2] = acc.z * inv;
    lds_out[hd][cb + 3] = acc.w * inv;
    __syncthreads();

    int c = tid;
    float outc = 0.25f * (lds_out[0][c] + lds_out[1][c] + lds_out[2][c] + lds_out[3][c]);
    float xrc = bf2f(xr[(size_t)n * DIMC + c]);
    float contrib = outc * W_beta[c] + xrc * W_beta[DIMC + c] + (outc - xrc) * W_beta[2 * DIMC + c];
#pragma unroll
    for (int msk = 32; msk >= 1; msk >>= 1) contrib += __shfl_xor(contrib, msk, 64);
    __shared__ float red[NHEAD];
    if (lane == 0) red[hd] = contrib;
    __syncthreads();
    float ssum = red[0] + red[1] + red[2] + red[3];
    float beta = 1.0f / (1.0f + __expf(-ssum));
    float tv = beta * xrc + (1.0f - beta) * outc;
    tf[(size_t)n * DIMC + c] = f2bf(fmaxf(tv, 0.f));
}

// ---------------- per-head fallback path (small workspace) ----------------

__global__ __launch_bounds__(256) void attn_head_kernel(const bf16u* __restrict__ qh,
                                                        const bf16u* __restrict__ kh,
                                                        const bf16u* __restrict__ vh,
                                                        const int* __restrict__ offsets,
                                                        const int* __restrict__ count,
                                                        const int* __restrict__ srcs,
                                                        float* __restrict__ outacc, int N) {
    int n = blockIdx.x * 4 + (threadIdx.x >> 6);
    if (n >= N) return;
    int lane = threadIdx.x & 63;
    int cb = lane * 4;
    const float scale = 0.0625f;

    float4 qf = load_bf4(qh + (size_t)n * DIMC + cb);
    qf.x *= scale; qf.y *= scale; qf.z *= scale; qf.w *= scale;

    int off = offsets[n], cnt = count[n];
    float m = -INFINITY, denom = 0.f;
    float4 acc = make_float4(0.f, 0.f, 0.f, 0.f);
    for (int i = 0; i < cnt; ++i) {
        int s = srcs[off + i];
        float4 kf = load_bf4(kh + (size_t)s * DIMC + cb);
        float d = qf.x * kf.x + qf.y * kf.y + qf.z * kf.z + qf.w * kf.w;
#pragma unroll
        for (int msk = 32; msk >= 1; msk >>= 1) d += __shfl_xor(d, msk, 64);
        float4 vf = load_bf4(vh + (size_t)s * DIMC + cb);
        float nm = fmaxf(m, d);
        float so = __expf(m - nm);
        float p = __expf(d - nm);
        denom = denom * so + p;
        acc.x = acc.x * so + p * vf.x;
        acc.y = acc.y * so + p * vf.y;
        acc.z = acc.z * so + p * vf.z;
        acc.w = acc.w * so + p * vf.w;
        m = nm;
    }
    float inv = 0.25f / fmaxf(denom, 1e-16f);
    float* o = outacc + (size_t)n * DIMC + cb;
    float4 cur = *(float4*)o;
    cur.x += acc.x * inv; cur.y += acc.y * inv;
    cur.z += acc.z * inv; cur.w += acc.w * inv;
    *(float4*)o = cur;
}

__global__ __launch_bounds__(256) void gate_kernel(const float* __restrict__ outacc,
                                                   const bf16u* __restrict__ xr,
                                                   const float* __restrict__ W_beta,
                                                   bf16u* __restrict__ tf) {
    int n = blockIdx.x;
    int c = threadIdx.x;
    int lane = c & 63, w = c >> 6;
    float outc = outacc[(size_t)n * DIMC + c];
    float xrc = bf2f(xr[(size_t)n * DIMC + c]);
    float contrib = outc * W_beta[c] + xrc * W_beta[DIMC + c] + (outc - xrc) * W_beta[2 * DIMC + c];
#pragma unroll
    for (int msk = 32; msk >= 1; msk >>= 1) contrib += __shfl_xor(contrib, msk, 64);
    __shared__ float red[NHEAD];
    if (lane == 0) red[w] = contrib;
    __syncthreads();
    float ssum = red[0] + red[1] + red[2] + red[3];
    float beta = 1.0f / (1.0f + __expf(-ssum));
    float tv = beta * xrc + (1.0f - beta) * outc;
    tf[(size_t)n * DIMC + c] = f2bf(fmaxf(tv, 0.f));
}

// ---------------- launch ----------------

static inline size_t align_up(size_t x) { return (x + 255) & ~(size_t)255; }

extern "C" void kernel_launch(void* const* d_in, const int* in_sizes, int n_in,
                              void* d_out, int out_size, void* d_ws, size_t ws_size,
                              hipStream_t stream) {
    const float* f_all  = (const float*)d_in[0];
    const int*   eidx   = (const int*)d_in[1];
    const float* W_gcn  = (const float*)d_in[2];
    const float* b_gcn  = (const float*)d_in[3];
    const float* W_q    = (const float*)d_in[4];
    const float* b_q    = (const float*)d_in[5];
    const float* W_k    = (const float*)d_in[6];
    const float* b_k    = (const float*)d_in[7];
    const float* W_v    = (const float*)d_in[8];
    const float* b_v    = (const float*)d_in[9];
    const float* W_skip = (const float*)d_in[10];
    const float* b_skip = (const float*)d_in[11];
    const float* W_beta = (const float*)d_in[12];
    const float* W_cnn  = (const float*)d_in[13];
    const float* b_cnn  = (const float*)d_in[14];

    const int N = in_sizes[0] / DIMC;
    const int E = in_sizes[1] / 2;
    const int* src = eidx;
    const int* dst = eidx + E;

    char* p = (char*)d_ws;
    auto alloc = [&](size_t bytes) { char* r = p; p += align_up(bytes); return r; };
    int*   count   = (int*)alloc((size_t)N * 4);
    int*   cursor  = (int*)alloc((size_t)N * 4);
    int*   offsets = (int*)alloc((size_t)N * 4);
    int*   srcs    = (int*)alloc((size_t)E * 4);
    float* dinv    = (float*)alloc((size_t)N * 4);
    bf16u* WgcnT   = (bf16u*)alloc(256 * 256 * 2);
    bf16u* WqkvT   = (bf16u*)alloc((size_t)3072 * 256 * 2);  // rows: Wq 0-1023, Wk, Wv
    float* bqkv    = (float*)alloc(3072 * 4);
    bf16u* WskipT  = (bf16u*)alloc(256 * 256 * 2);
    bf16u* Wcnn_b  = (bf16u*)alloc(256 * 256 * 2);
    bf16u* xbuf    = (bf16u*)alloc((size_t)N * DIMC * 2);  // f_all bf16, then x
    bf16u* h       = (bf16u*)alloc((size_t)N * DIMC * 2);  // then tf
    bf16u* xr      = (bf16u*)alloc((size_t)N * DIMC * 2);

    size_t used = (size_t)(p - (char*)d_ws);
    bool fused = used + align_up((size_t)N * 3072 * 2) <= ws_size;

    hipMemsetAsync(count, 0, (size_t)N * 4, stream);
    hipMemsetAsync(cursor, 0, (size_t)N * 4, stream);

    int eblocks = (E + 255) / 256;
    count_kernel<<<eblocks, 256, 0, stream>>>(dst, count, E);
    scan_kernel<<<1, 1024, 0, stream>>>(count, offsets, dinv, N);
    fill_kernel<<<eblocks, 256, 0, stream>>>(src, dst, offsets, cursor, srcs, E);

    // weight prep: BT bf16 [Nc][256]
    cvt_kernel<<<((N * DIMC / 4) + 255) / 256, 256, 0, stream>>>(f_all, xbuf, N * DIMC / 4);
    transpose_cvt_kernel<<<256, 256, 0, stream>>>(W_gcn, WgcnT, 256);
    transpose_cvt_kernel<<<1024, 256, 0, stream>>>(W_q, WqkvT, 1024);
    transpose_cvt_kernel<<<1024, 256, 0, stream>>>(W_k, WqkvT + 1024 * 256, 1024);
    transpose_cvt_kernel<<<1024, 256, 0, stream>>>(W_v, WqkvT + 2048 * 256, 1024);
    concat_bias_kernel<<<12, 256, 0, stream>>>(b_q, b_k, b_v, bqkv);
    transpose_cvt_kernel<<<256, 256, 0, stream>>>(W_skip, WskipT, 256);
    cvt_kernel<<<(256 * 256 / 4 + 255) / 256, 256, 0, stream>>>(W_cnn, Wcnn_b, 256 * 256 / 4);

    int mby = (N + 127) / 128;
    // h = bf16(f_all @ W_gcn)
    gemm_tile<false><<<dim3(2, mby), 256, 0, stream>>>(xbuf, WgcnT, nullptr, h, N, 256, 256);
    // x = relu(GCN-agg + b_gcn) -> xbuf
    gcn_agg_kernel<<<N, 256, 0, stream>>>(h, dinv, offsets, count, srcs, b_gcn, xbuf);

    if (fused) {
        bf16u* qkv = (bf16u*)alloc((size_t)N * 3072 * 2);
        gemm_tile<false><<<dim3(24, mby), 256, 0, stream>>>(xbuf, WqkvT, bqkv, qkv, N, 3072, 3072);
        gemm_tile<false><<<dim3(2, mby), 256, 0, stream>>>(xbuf, WskipT, b_skip, xr, N, 256, 256);
        transformer_kernel<<<N, 256, 0, stream>>>(qkv, qkv + 1024, qkv + 2048, 3072, xr, W_beta,
                                                  offsets, count, srcs, h);
    } else {
        bf16u* qh = (bf16u*)alloc((size_t)N * DIMC * 2);
        bf16u* kh = (bf16u*)alloc((size_t)N * DIMC * 2);
        bf16u* vh = (bf16u*)alloc((size_t)N * DIMC * 2);
        float* outacc = (float*)alloc((size_t)N * DIMC * 4);
        hipMemsetAsync(outacc, 0, (size_t)N * DIMC * 4, stream);
        for (int hd = 0; hd < NHEAD; ++hd) {
            gemm_tile<false><<<dim3(2, mby), 256, 0, stream>>>(xbuf, WqkvT + (size_t)hd * 256 * 256,
                                                               b_q + hd * 256, qh, N, 256, 256);
            gemm_tile<false><<<dim3(2, mby), 256, 0, stream>>>(xbuf, WqkvT + (size_t)(1024 + hd * 256) * 256,
                                                               b_k + hd * 256, kh, N, 256, 256);
            gemm_tile<false><<<dim3(2, mby), 256, 0, stream>>>(xbuf, WqkvT + (size_t)(2048 + hd * 256) * 256,
                                                               b_v + hd * 256, vh, N, 256, 256);
            attn_head_kernel<<<(N + 3) / 4, 256, 0, stream>>>(qh, kh, vh, offsets, count, srcs, outacc, N);
        }
        gemm_tile<false><<<dim3(2, mby), 256, 0, stream>>>(xbuf, WskipT, b_skip, xr, N, 256, 256);
        gate_kernel<<<N, 256, 0, stream>>>(outacc, xr, W_beta, h);
    }

    // out[c*N+n] = W_cnn @ tf^T + b_cnn   (tf lives in h)
    gemm_tile<true><<<dim3((N + 127) / 128, 2), 256, 0, stream>>>(Wcnn_b, h, b_cnn, (float*)d_out, 256, N, N);
}

// Round 6
// 325.230 us; speedup vs baseline: 2.8060x; 1.2649x over previous
//
#include <hip/hip_runtime.h>
#include <math.h>

#define DIMC 256
#define NHEAD 4

typedef unsigned short bf16u;
typedef __attribute__((ext_vector_type(8))) short bf16x8;
typedef __attribute__((ext_vector_type(4))) float f32x4;

__device__ __forceinline__ float bf2f(bf16u u) {
    union { float f; unsigned int i; } c; c.i = ((unsigned int)u) << 16; return c.f;
}
__device__ __forceinline__ bf16u f2bf(float f) {
    union { float f; unsigned int i; } c; c.f = f;
    unsigned int r = c.i + 0x7fffu + ((c.i >> 16) & 1u);
    return (bf16u)(r >> 16);
}
__device__ __forceinline__ float4 load_bf4(const bf16u* p) {
    ushort4 raw = *(const ushort4*)p;
    return make_float4(bf2f(raw.x), bf2f(raw.y), bf2f(raw.z), bf2f(raw.w));
}
__device__ __forceinline__ void store_bf4(bf16u* p, float4 v) {
    ushort4 raw;
    raw.x = f2bf(v.x); raw.y = f2bf(v.y); raw.z = f2bf(v.z); raw.w = f2bf(v.w);
    *(ushort4*)p = raw;
}

// ---------------- graph preprocessing: CSR by dst ----------------

__global__ void count_kernel(const int* __restrict__ dst, int* __restrict__ count, int E) {
    int e = blockIdx.x * 256 + threadIdx.x;
    if (e < E) atomicAdd(&count[dst[e]], 1);
}

__global__ __launch_bounds__(1024) void scan_kernel(const int* __restrict__ count,
                                                    int* __restrict__ offsets,
                                                    float* __restrict__ dinv, int n) {
    __shared__ int part[1024];
    int t = threadIdx.x;
    int CH = (n + 1023) >> 10;
    int base = t * CH;
    int s = 0;
    for (int i = 0; i < CH; ++i) { int idx = base + i; if (idx < n) s += count[idx]; }
    part[t] = s;
    __syncthreads();
    for (int off = 1; off < 1024; off <<= 1) {
        int v = (t >= off) ? part[t - off] : 0;
        __syncthreads();
        part[t] += v;
        __syncthreads();
    }
    int run = part[t] - s;
    for (int i = 0; i < CH; ++i) {
        int idx = base + i;
        if (idx < n) {
            offsets[idx] = run;
            int c = count[idx];
            run += c;
            dinv[idx] = rsqrtf((float)(c + 1));
        }
    }
}

__global__ void fill_kernel(const int* __restrict__ src, const int* __restrict__ dst,
                            const int* __restrict__ offsets, int* __restrict__ cursor,
                            int* __restrict__ srcs, int E) {
    int e = blockIdx.x * 256 + threadIdx.x;
    if (e < E) {
        int d = dst[e];
        int pos = atomicAdd(&cursor[d], 1);
        srcs[offsets[d] + pos] = src[e];
    }
}

// ---------------- fused preprocessing ----------------

__global__ __launch_bounds__(256) void prep_kernel(const float* __restrict__ f_all, int n4_f,
                                                   const float* __restrict__ W_gcn,
                                                   const float* __restrict__ W_q,
                                                   const float* __restrict__ W_k,
                                                   const float* __restrict__ W_v,
                                                   const float* __restrict__ W_skip,
                                                   const float* __restrict__ W_cnn,
                                                   const float* __restrict__ b_q,
                                                   const float* __restrict__ b_k,
                                                   const float* __restrict__ b_v,
                                                   const float* __restrict__ b_skip,
                                                   bf16u* __restrict__ xbuf,
                                                   bf16u* __restrict__ WgcnT,
                                                   bf16u* __restrict__ WqkvsT,
                                                   bf16u* __restrict__ Wcnn_b,
                                                   float* __restrict__ bqkvs) {
    int b = blockIdx.x, t = threadIdx.x;
    int nf = (n4_f + 255) >> 8;
    if (b < nf) {
        int i = b * 256 + t;
        if (i < n4_f) {
            float4 vv = *(const float4*)(f_all + (size_t)i * 4);
            store_bf4(xbuf + (size_t)i * 4, vv);
        }
        return;
    }
    b -= nf;
    if (b < 3328) {
        const float* Wsrc; int col, ldw;
        if (b < 1024)      { Wsrc = W_q;    col = b;        ldw = 1024; }
        else if (b < 2048) { Wsrc = W_k;    col = b - 1024; ldw = 1024; }
        else if (b < 3072) { Wsrc = W_v;    col = b - 2048; ldw = 1024; }
        else               { Wsrc = W_skip; col = b - 3072; ldw = 256;  }
        WqkvsT[(size_t)b * 256 + t] = f2bf(Wsrc[(size_t)t * ldw + col]);
        return;
    }
    b -= 3328;
    if (b < 256) { WgcnT[(size_t)b * 256 + t] = f2bf(W_gcn[(size_t)t * 256 + b]); return; }
    b -= 256;
    if (b < 64) {
        int i = b * 256 + t;
        float4 vv = *(const float4*)(W_cnn + (size_t)i * 4);
        store_bf4(Wcnn_b + (size_t)i * 4, vv);
        return;
    }
    b -= 64;
    int i = b * 256 + t;
    if (i < 3328)
        bqkvs[i] = (i < 1024) ? b_q[i] : (i < 2048) ? b_k[i - 1024]
                 : (i < 3072) ? b_v[i - 2048] : b_skip[i - 3072];
}

// ---------------- LDS-staged MFMA GEMM, 128x128 tile, BK=32 ----------------
// C[M x Nc] = A_bf16[M x 256] @ (BT_bf16[Nc x 256])^T (+bias)
// ROWBIAS=false: bf16 out, col bias, LDS-staged coalesced 16B stores (separate Cs buffer —
//                NO aliasing overlay; r5's cast-overlay of As caused post-warmup corruption).
// ROWBIAS=true : f32 out, row bias, direct stores (64B segments, coalesced already).

template <bool ROWBIAS>
__global__ __launch_bounds__(256) void gemm_tile(const bf16u* __restrict__ A,
                                                 const bf16u* __restrict__ BT,
                                                 const float* __restrict__ bias,
                                                 void* __restrict__ Cout,
                                                 int M, int Nc, int ldc) {
    __shared__ __align__(16) bf16u As[128][32];
    __shared__ __align__(16) bf16u Bs[128][32];
    int t = threadIdx.x;
    int w = t >> 6, lane = t & 63;
    int q = lane >> 4, r = lane & 15;
    int wm = (w & 1) * 64, wn = (w >> 1) * 64;
    int bm = blockIdx.y * 128, bn = blockIdx.x * 128;

    int srow = t >> 2, scol = (t & 3) * 8;
    int arow0 = bm + srow;      if (arow0 >= M)  arow0 = M - 1;
    int arow1 = bm + 64 + srow; if (arow1 >= M)  arow1 = M - 1;
    int brow0 = bn + srow;      if (brow0 >= Nc) brow0 = Nc - 1;
    int brow1 = bn + 64 + srow; if (brow1 >= Nc) brow1 = Nc - 1;
    const bf16u* a0 = A + (size_t)arow0 * DIMC + scol;
    const bf16u* a1 = A + (size_t)arow1 * DIMC + scol;
    const bf16u* b0 = BT + (size_t)brow0 * DIMC + scol;
    const bf16u* b1 = BT + (size_t)brow1 * DIMC + scol;

    f32x4 acc[4][4] = {};
    bf16x8 va0 = *(const bf16x8*)(a0);
    bf16x8 va1 = *(const bf16x8*)(a1);
    bf16x8 vb0 = *(const bf16x8*)(b0);
    bf16x8 vb1 = *(const bf16x8*)(b1);
    for (int k0 = 0; k0 < DIMC; k0 += 32) {
        __syncthreads();
        *(bf16x8*)&As[srow][scol] = va0;
        *(bf16x8*)&As[64 + srow][scol] = va1;
        *(bf16x8*)&Bs[srow][scol] = vb0;
        *(bf16x8*)&Bs[64 + srow][scol] = vb1;
        __syncthreads();
        if (k0 + 32 < DIMC) {
            va0 = *(const bf16x8*)(a0 + k0 + 32);
            va1 = *(const bf16x8*)(a1 + k0 + 32);
            vb0 = *(const bf16x8*)(b0 + k0 + 32);
            vb1 = *(const bf16x8*)(b1 + k0 + 32);
        }
        bf16x8 af[4], bfr[4];
#pragma unroll
        for (int i = 0; i < 4; ++i) af[i] = *(const bf16x8*)&As[wm + i * 16 + r][q * 8];
#pragma unroll
        for (int j = 0; j < 4; ++j) bfr[j] = *(const bf16x8*)&Bs[wn + j * 16 + r][q * 8];
#pragma unroll
        for (int i = 0; i < 4; ++i)
#pragma unroll
            for (int j = 0; j < 4; ++j)
                acc[i][j] = __builtin_amdgcn_mfma_f32_16x16x32_bf16(af[i], bfr[j], acc[i][j], 0, 0, 0);
    }

    if (ROWBIAS) {
        float* C = (float*)Cout;
#pragma unroll
        for (int j = 0; j < 4; ++j) {
            int col = bn + wn + j * 16 + r;
            if (col >= Nc) continue;
#pragma unroll
            for (int i = 0; i < 4; ++i)
#pragma unroll
                for (int rg = 0; rg < 4; ++rg) {
                    int row = bm + wm + i * 16 + q * 4 + rg;
                    if (row < M) C[(size_t)row * ldc + col] = acc[i][j][rg] + bias[row];
                }
        }
    } else {
        // dedicated staging buffer — no aliasing with As/Bs
        __shared__ __align__(16) bf16u Cs[32][128];
        bf16u* C = (bf16u*)Cout;
        float cb4[4];
#pragma unroll
        for (int j = 0; j < 4; ++j) {
            int col = bn + wn + j * 16 + r;
            cb4[j] = bias ? bias[col] : 0.0f;
        }
        int rhalf = (w & 1) * 16;
        int colbase = (w >> 1) * 64;
        __syncthreads();
#pragma unroll
        for (int i = 0; i < 4; ++i) {
#pragma unroll
            for (int j = 0; j < 4; ++j)
#pragma unroll
                for (int rg = 0; rg < 4; ++rg)
                    Cs[rhalf + q * 4 + rg][colbase + j * 16 + r] = f2bf(acc[i][j][rg] + cb4[j]);
            __syncthreads();
#pragma unroll
            for (int cpass = 0; cpass < 2; ++cpass) {
                int chunk = cpass * 256 + t;   // 0..511 over 32 rows x 16 chunks
                int sr = chunk >> 4;
                int c16 = chunk & 15;
                int grow = bm + (sr < 16 ? i * 16 + sr : 64 + i * 16 + (sr - 16));
                if (grow < M)
                    *(bf16x8*)&C[(size_t)grow * ldc + bn + c16 * 8] = *(const bf16x8*)&Cs[sr][c16 * 8];
            }
            __syncthreads();
        }
    }
}

// ---------------- GCN aggregation: wave per node ----------------

__global__ __launch_bounds__(256) void gcn_agg_kernel(const bf16u* __restrict__ h,
                                                      const float* __restrict__ dinv,
                                                      const int* __restrict__ offsets,
                                                      const int* __restrict__ count,
                                                      const int* __restrict__ srcs,
                                                      const float* __restrict__ b_gcn,
                                                      bf16u* __restrict__ x, int N) {
    int n = blockIdx.x * 4 + (threadIdx.x >> 6);
    if (n >= N) return;
    int lane = threadIdx.x & 63;
    int cb = lane * 4;
    float dn = dinv[n];
    float4 hn = load_bf4(h + (size_t)n * DIMC + cb);
    int off = offsets[n], cnt = count[n];
    float4 acc = make_float4(0.f, 0.f, 0.f, 0.f);
    int s_next = (cnt > 0) ? srcs[off] : 0;
    for (int i = 0; i < cnt; ++i) {
        int s = s_next;
        if (i + 1 < cnt) s_next = srcs[off + i + 1];
        float ds = dinv[s];
        float4 hv = load_bf4(h + (size_t)s * DIMC + cb);
        acc.x += hv.x * ds; acc.y += hv.y * ds;
        acc.z += hv.z * ds; acc.w += hv.w * ds;
    }
    float4 bg = *(const float4*)(b_gcn + cb);
    float dnn = dn * dn;
    float4 o;
    o.x = fmaxf(dn * acc.x + hn.x * dnn + bg.x, 0.f);
    o.y = fmaxf(dn * acc.y + hn.y * dnn + bg.y, 0.f);
    o.z = fmaxf(dn * acc.z + hn.z * dnn + bg.z, 0.f);
    o.w = fmaxf(dn * acc.w + hn.w * dnn + bg.w, 0.f);
    store_bf4(x + (size_t)n * DIMC + cb, o);
}

// ---------------- FUSED transformer: heads + online softmax + beta gate ----------------

__global__ __launch_bounds__(256) void transformer_kernel(const bf16u* __restrict__ q,
                                                          const bf16u* __restrict__ k,
                                                          const bf16u* __restrict__ v,
                                                          int stride,
                                                          const bf16u* __restrict__ xr,
                                                          int xr_stride,
                                                          const float* __restrict__ W_beta,
                                                          const int* __restrict__ offsets,
                                                          const int* __restrict__ count,
                                                          const int* __restrict__ srcs,
                                                          bf16u* __restrict__ tf) {
    int n = blockIdx.x;
    int tid = threadIdx.x;
    int hd = tid >> 6;
    int lane = tid & 63;
    int cb = lane * 4;
    const float scale = 0.0625f;  // 1/sqrt(256)

    float4 qf = load_bf4(q + (size_t)n * stride + hd * DIMC + cb);
    qf.x *= scale; qf.y *= scale; qf.z *= scale; qf.w *= scale;

    int off = offsets[n], cnt = count[n];
    float m = -INFINITY, denom = 0.f;
    float4 acc = make_float4(0.f, 0.f, 0.f, 0.f);
    int s_next = (cnt > 0) ? srcs[off] : 0;
    for (int i = 0; i < cnt; ++i) {
        int s = s_next;
        if (i + 1 < cnt) s_next = srcs[off + i + 1];
        float4 kf = load_bf4(k + (size_t)s * stride + hd * DIMC + cb);
        float4 vf = load_bf4(v + (size_t)s * stride + hd * DIMC + cb);
        float d = qf.x * kf.x + qf.y * kf.y + qf.z * kf.z + qf.w * kf.w;
#pragma unroll
        for (int msk = 32; msk >= 1; msk >>= 1) d += __shfl_xor(d, msk, 64);
        float nm = fmaxf(m, d);
        float so = __expf(m - nm);
        float p = __expf(d - nm);
        denom = denom * so + p;
        acc.x = acc.x * so + p * vf.x;
        acc.y = acc.y * so + p * vf.y;
        acc.z = acc.z * so + p * vf.z;
        acc.w = acc.w * so + p * vf.w;
        m = nm;
    }
    float inv = 1.0f / fmaxf(denom, 1e-16f);

    __shared__ float lds_out[NHEAD][DIMC];
    lds_out[hd][cb + 0] = acc.x * inv;
    lds_out[hd][cb + 1] = acc.y * inv;
    lds_out[hd][cb + 2] = acc.z * inv;
    lds_out[hd][cb + 3] = acc.w * inv;
    __syncthreads();

    int c = tid;
    float outc = 0.25f * (lds_out[0][c] + lds_out[1][c] + lds_out[2][c] + lds_out[3][c]);
    float xrc = bf2f(xr[(size_t)n * xr_stride + c]);
    float contrib = outc * W_beta[c] + xrc * W_beta[DIMC + c] + (outc - xrc) * W_beta[2 * DIMC + c];
#pragma unroll
    for (int msk = 32; msk >= 1; msk >>= 1) contrib += __shfl_xor(contrib, msk, 64);
    __shared__ float red[NHEAD];
    if (lane == 0) red[hd] = contrib;
    __syncthreads();
    float ssum = red[0] + red[1] + red[2] + red[3];
    float beta = 1.0f / (1.0f + __expf(-ssum));
    float tv = beta * xrc + (1.0f - beta) * outc;
    tf[(size_t)n * DIMC + c] = f2bf(fmaxf(tv, 0.f));
}

// ---------------- launch ----------------

static inline size_t align_up(size_t x) { return (x + 255) & ~(size_t)255; }

extern "C" void kernel_launch(void* const* d_in, const int* in_sizes, int n_in,
                              void* d_out, int out_size, void* d_ws, size_t ws_size,
                              hipStream_t stream) {
    const float* f_all  = (const float*)d_in[0];
    const int*   eidx   = (const int*)d_in[1];
    const float* W_gcn  = (const float*)d_in[2];
    const float* b_gcn  = (const float*)d_in[3];
    const float* W_q    = (const float*)d_in[4];
    const float* b_q    = (const float*)d_in[5];
    const float* W_k    = (const float*)d_in[6];
    const float* b_k    = (const float*)d_in[7];
    const float* W_v    = (const float*)d_in[8];
    const float* b_v    = (const float*)d_in[9];
    const float* W_skip = (const float*)d_in[10];
    const float* b_skip = (const float*)d_in[11];
    const float* W_beta = (const float*)d_in[12];
    const float* W_cnn  = (const float*)d_in[13];
    const float* b_cnn  = (const float*)d_in[14];

    const int N = in_sizes[0] / DIMC;
    const int E = in_sizes[1] / 2;
    const int* src = eidx;
    const int* dst = eidx + E;

    char* p = (char*)d_ws;
    auto alloc = [&](size_t bytes) { char* r = p; p += align_up(bytes); return r; };
    int*   count   = (int*)alloc((size_t)N * 4);
    int*   cursor  = (int*)alloc((size_t)N * 4);
    int*   offsets = (int*)alloc((size_t)N * 4);
    int*   srcs    = (int*)alloc((size_t)E * 4);
    float* dinv    = (float*)alloc((size_t)N * 4);
    bf16u* WgcnT   = (bf16u*)alloc(256 * 256 * 2);
    bf16u* WqkvsT  = (bf16u*)alloc((size_t)3328 * 256 * 2);  // Wq^T|Wk^T|Wv^T|Wskip^T
    float* bqkvs   = (float*)alloc(3328 * 4);
    bf16u* Wcnn_b  = (bf16u*)alloc(256 * 256 * 2);
    bf16u* xbuf    = (bf16u*)alloc((size_t)N * DIMC * 2);    // f_all bf16, then x
    bf16u* h       = (bf16u*)alloc((size_t)N * DIMC * 2);    // then tf
    bf16u* qkvs    = (bf16u*)alloc((size_t)N * 3328 * 2);    // q|k|v|xr

    hipMemsetAsync(count, 0, (size_t)N * 4, stream);
    hipMemsetAsync(cursor, 0, (size_t)N * 4, stream);

    int eblocks = (E + 255) / 256;
    count_kernel<<<eblocks, 256, 0, stream>>>(dst, count, E);
    scan_kernel<<<1, 1024, 0, stream>>>(count, offsets, dinv, N);
    fill_kernel<<<eblocks, 256, 0, stream>>>(src, dst, offsets, cursor, srcs, E);

    int n4_f = N * DIMC / 4;
    int nf = (n4_f + 255) >> 8;
    prep_kernel<<<nf + 3328 + 256 + 64 + 13, 256, 0, stream>>>(
        f_all, n4_f, W_gcn, W_q, W_k, W_v, W_skip, W_cnn,
        b_q, b_k, b_v, b_skip, xbuf, WgcnT, WqkvsT, Wcnn_b, bqkvs);

    int mby = (N + 127) / 128;
    // h = bf16(f_all @ W_gcn)
    gemm_tile<false><<<dim3(2, mby), 256, 0, stream>>>(xbuf, WgcnT, nullptr, h, N, 256, 256);
    // x = relu(GCN-agg + b_gcn) -> xbuf
    gcn_agg_kernel<<<(N + 3) / 4, 256, 0, stream>>>(h, dinv, offsets, count, srcs, b_gcn, xbuf, N);
    // qkvs = x @ [Wq|Wk|Wv|Wskip] + [bq|bk|bv|bskip]
    gemm_tile<false><<<dim3(26, mby), 256, 0, stream>>>(xbuf, WqkvsT, bqkvs, qkvs, N, 3328, 3328);
    // transformer + beta gate -> tf (in h)
    transformer_kernel<<<N, 256, 0, stream>>>(qkvs, qkvs + 1024, qkvs + 2048, 3328,
                                              qkvs + 3072, 3328, W_beta,
                                              offsets, count, srcs, h);
    // out[c*N+n] = W_cnn @ tf^T + b_cnn
    gemm_tile<true><<<dim3((N + 127) / 128, 2), 256, 0, stream>>>(Wcnn_b, h, b_cnn, (float*)d_out, 256, N, N);
}

// Round 7
// 320.401 us; speedup vs baseline: 2.8483x; 1.0151x over previous
//
#include <hip/hip_runtime.h>
#include <math.h>

#define DIMC 256
#define NHEAD 4

typedef unsigned short bf16u;
typedef __attribute__((ext_vector_type(8))) short bf16x8;
typedef __attribute__((ext_vector_type(4))) float f32x4;

__device__ __forceinline__ float bf2f(bf16u u) {
    union { float f; unsigned int i; } c; c.i = ((unsigned int)u) << 16; return c.f;
}
__device__ __forceinline__ bf16u f2bf(float f) {
    union { float f; unsigned int i; } c; c.f = f;
    unsigned int r = c.i + 0x7fffu + ((c.i >> 16) & 1u);
    return (bf16u)(r >> 16);
}
__device__ __forceinline__ float4 load_bf4(const bf16u* p) {
    ushort4 raw = *(const ushort4*)p;
    return make_float4(bf2f(raw.x), bf2f(raw.y), bf2f(raw.z), bf2f(raw.w));
}
__device__ __forceinline__ void store_bf4(bf16u* p, float4 v) {
    ushort4 raw;
    raw.x = f2bf(v.x); raw.y = f2bf(v.y); raw.z = f2bf(v.z); raw.w = f2bf(v.w);
    *(ushort4*)p = raw;
}
__device__ __forceinline__ void load_bf8(const bf16u* p, float* o) {
    bf16x8 raw = *(const bf16x8*)p;
#pragma unroll
    for (int i = 0; i < 8; ++i) {
        union { float f; unsigned int u; } c;
        c.u = ((unsigned int)(unsigned short)raw[i]) << 16;
        o[i] = c.f;
    }
}
__device__ __forceinline__ void store_bf8(bf16u* p, const float* v) {
    bf16x8 raw;
#pragma unroll
    for (int i = 0; i < 8; ++i) raw[i] = (short)f2bf(v[i]);
    *(bf16x8*)p = raw;
}

// ---------------- graph preprocessing: CSR by dst ----------------

__global__ void count_kernel(const int* __restrict__ dst, int* __restrict__ count, int E) {
    int e = blockIdx.x * 256 + threadIdx.x;
    if (e < E) atomicAdd(&count[dst[e]], 1);
}

__global__ __launch_bounds__(1024) void scan_kernel(const int* __restrict__ count,
                                                    int* __restrict__ offsets,
                                                    float* __restrict__ dinv, int n) {
    __shared__ int part[1024];
    int t = threadIdx.x;
    int CH = (n + 1023) >> 10;
    int base = t * CH;
    int s = 0;
    for (int i = 0; i < CH; ++i) { int idx = base + i; if (idx < n) s += count[idx]; }
    part[t] = s;
    __syncthreads();
    for (int off = 1; off < 1024; off <<= 1) {
        int v = (t >= off) ? part[t - off] : 0;
        __syncthreads();
        part[t] += v;
        __syncthreads();
    }
    int run = part[t] - s;
    for (int i = 0; i < CH; ++i) {
        int idx = base + i;
        if (idx < n) {
            offsets[idx] = run;
            int c = count[idx];
            run += c;
            dinv[idx] = rsqrtf((float)(c + 1));
        }
    }
}

__global__ void fill_kernel(const int* __restrict__ src, const int* __restrict__ dst,
                            const int* __restrict__ offsets, int* __restrict__ cursor,
                            int* __restrict__ srcs, int E) {
    int e = blockIdx.x * 256 + threadIdx.x;
    if (e < E) {
        int d = dst[e];
        int pos = atomicAdd(&cursor[d], 1);
        srcs[offsets[d] + pos] = src[e];
    }
}

// ---------------- fused preprocessing ----------------

__global__ __launch_bounds__(256) void prep_kernel(const float* __restrict__ f_all, int n4_f,
                                                   const float* __restrict__ W_gcn,
                                                   const float* __restrict__ W_q,
                                                   const float* __restrict__ W_k,
                                                   const float* __restrict__ W_v,
                                                   const float* __restrict__ W_skip,
                                                   const float* __restrict__ W_cnn,
                                                   const float* __restrict__ b_q,
                                                   const float* __restrict__ b_k,
                                                   const float* __restrict__ b_v,
                                                   const float* __restrict__ b_skip,
                                                   bf16u* __restrict__ xbuf,
                                                   bf16u* __restrict__ WgcnT,
                                                   bf16u* __restrict__ WqkvsT,
                                                   bf16u* __restrict__ Wcnn_b,
                                                   float* __restrict__ bqkvs) {
    int b = blockIdx.x, t = threadIdx.x;
    int nf = (n4_f + 255) >> 8;
    if (b < nf) {
        int i = b * 256 + t;
        if (i < n4_f) {
            float4 vv = *(const float4*)(f_all + (size_t)i * 4);
            store_bf4(xbuf + (size_t)i * 4, vv);
        }
        return;
    }
    b -= nf;
    if (b < 3328) {
        const float* Wsrc; int col, ldw;
        if (b < 1024)      { Wsrc = W_q;    col = b;        ldw = 1024; }
        else if (b < 2048) { Wsrc = W_k;    col = b - 1024; ldw = 1024; }
        else if (b < 3072) { Wsrc = W_v;    col = b - 2048; ldw = 1024; }
        else               { Wsrc = W_skip; col = b - 3072; ldw = 256;  }
        WqkvsT[(size_t)b * 256 + t] = f2bf(Wsrc[(size_t)t * ldw + col]);
        return;
    }
    b -= 3328;
    if (b < 256) { WgcnT[(size_t)b * 256 + t] = f2bf(W_gcn[(size_t)t * 256 + b]); return; }
    b -= 256;
    if (b < 64) {
        int i = b * 256 + t;
        float4 vv = *(const float4*)(W_cnn + (size_t)i * 4);
        store_bf4(Wcnn_b + (size_t)i * 4, vv);
        return;
    }
    b -= 64;
    int i = b * 256 + t;
    if (i < 3328)
        bqkvs[i] = (i < 1024) ? b_q[i] : (i < 2048) ? b_k[i - 1024]
                 : (i < 3072) ? b_v[i - 2048] : b_skip[i - 3072];
}

// ---------------- LDS-staged MFMA GEMM, 128x128 tile, BK=32 ----------------

template <bool ROWBIAS>
__global__ __launch_bounds__(256) void gemm_tile(const bf16u* __restrict__ A,
                                                 const bf16u* __restrict__ BT,
                                                 const float* __restrict__ bias,
                                                 void* __restrict__ Cout,
                                                 int M, int Nc, int ldc) {
    __shared__ __align__(16) bf16u As[128][32];
    __shared__ __align__(16) bf16u Bs[128][32];
    int t = threadIdx.x;
    int w = t >> 6, lane = t & 63;
    int q = lane >> 4, r = lane & 15;
    int wm = (w & 1) * 64, wn = (w >> 1) * 64;
    int bm = blockIdx.y * 128, bn = blockIdx.x * 128;

    int srow = t >> 2, scol = (t & 3) * 8;
    int arow0 = bm + srow;      if (arow0 >= M)  arow0 = M - 1;
    int arow1 = bm + 64 + srow; if (arow1 >= M)  arow1 = M - 1;
    int brow0 = bn + srow;      if (brow0 >= Nc) brow0 = Nc - 1;
    int brow1 = bn + 64 + srow; if (brow1 >= Nc) brow1 = Nc - 1;
    const bf16u* a0 = A + (size_t)arow0 * DIMC + scol;
    const bf16u* a1 = A + (size_t)arow1 * DIMC + scol;
    const bf16u* b0 = BT + (size_t)brow0 * DIMC + scol;
    const bf16u* b1 = BT + (size_t)brow1 * DIMC + scol;

    f32x4 acc[4][4] = {};
    bf16x8 va0 = *(const bf16x8*)(a0);
    bf16x8 va1 = *(const bf16x8*)(a1);
    bf16x8 vb0 = *(const bf16x8*)(b0);
    bf16x8 vb1 = *(const bf16x8*)(b1);
    for (int k0 = 0; k0 < DIMC; k0 += 32) {
        __syncthreads();
        *(bf16x8*)&As[srow][scol] = va0;
        *(bf16x8*)&As[64 + srow][scol] = va1;
        *(bf16x8*)&Bs[srow][scol] = vb0;
        *(bf16x8*)&Bs[64 + srow][scol] = vb1;
        __syncthreads();
        if (k0 + 32 < DIMC) {
            va0 = *(const bf16x8*)(a0 + k0 + 32);
            va1 = *(const bf16x8*)(a1 + k0 + 32);
            vb0 = *(const bf16x8*)(b0 + k0 + 32);
            vb1 = *(const bf16x8*)(b1 + k0 + 32);
        }
        bf16x8 af[4], bfr[4];
#pragma unroll
        for (int i = 0; i < 4; ++i) af[i] = *(const bf16x8*)&As[wm + i * 16 + r][q * 8];
#pragma unroll
        for (int j = 0; j < 4; ++j) bfr[j] = *(const bf16x8*)&Bs[wn + j * 16 + r][q * 8];
#pragma unroll
        for (int i = 0; i < 4; ++i)
#pragma unroll
            for (int j = 0; j < 4; ++j)
                acc[i][j] = __builtin_amdgcn_mfma_f32_16x16x32_bf16(af[i], bfr[j], acc[i][j], 0, 0, 0);
    }

    if (ROWBIAS) {
        float* C = (float*)Cout;
#pragma unroll
        for (int j = 0; j < 4; ++j) {
            int col = bn + wn + j * 16 + r;
            if (col >= Nc) continue;
#pragma unroll
            for (int i = 0; i < 4; ++i)
#pragma unroll
                for (int rg = 0; rg < 4; ++rg) {
                    int row = bm + wm + i * 16 + q * 4 + rg;
                    if (row < M) C[(size_t)row * ldc + col] = acc[i][j][rg] + bias[row];
                }
        }
    } else {
        __shared__ __align__(16) bf16u Cs[32][128];
        bf16u* C = (bf16u*)Cout;
        float cb4[4];
#pragma unroll
        for (int j = 0; j < 4; ++j) {
            int col = bn + wn + j * 16 + r;
            cb4[j] = bias ? bias[col] : 0.0f;
        }
        int rhalf = (w & 1) * 16;
        int colbase = (w >> 1) * 64;
        __syncthreads();
#pragma unroll
        for (int i = 0; i < 4; ++i) {
#pragma unroll
            for (int j = 0; j < 4; ++j)
#pragma unroll
                for (int rg = 0; rg < 4; ++rg)
                    Cs[rhalf + q * 4 + rg][colbase + j * 16 + r] = f2bf(acc[i][j][rg] + cb4[j]);
            __syncthreads();
#pragma unroll
            for (int cpass = 0; cpass < 2; ++cpass) {
                int chunk = cpass * 256 + t;
                int sr = chunk >> 4;
                int c16 = chunk & 15;
                int grow = bm + (sr < 16 ? i * 16 + sr : 64 + i * 16 + (sr - 16));
                if (grow < M)
                    *(bf16x8*)&C[(size_t)grow * ldc + bn + c16 * 8] = *(const bf16x8*)&Cs[sr][c16 * 8];
            }
            __syncthreads();
        }
    }
}

// ---------------- GCN aggregation: wave per node, unroll-2 ----------------

__global__ __launch_bounds__(256) void gcn_agg_kernel(const bf16u* __restrict__ h,
                                                      const float* __restrict__ dinv,
                                                      const int* __restrict__ offsets,
                                                      const int* __restrict__ count,
                                                      const int* __restrict__ srcs,
                                                      const float* __restrict__ b_gcn,
                                                      bf16u* __restrict__ x, int N) {
    int n = blockIdx.x * 4 + (threadIdx.x >> 6);
    if (n >= N) return;
    int lane = threadIdx.x & 63;
    int cb = lane * 4;
    float dn = dinv[n];
    float4 hn = load_bf4(h + (size_t)n * DIMC + cb);
    int off = offsets[n], cnt = count[n];
    float4 acc = make_float4(0.f, 0.f, 0.f, 0.f);
    int i = 0;
    for (; i + 2 <= cnt; i += 2) {
        int s0 = srcs[off + i], s1 = srcs[off + i + 1];
        float d0 = dinv[s0], d1 = dinv[s1];
        float4 h0 = load_bf4(h + (size_t)s0 * DIMC + cb);
        float4 h1 = load_bf4(h + (size_t)s1 * DIMC + cb);
        acc.x += h0.x * d0 + h1.x * d1;
        acc.y += h0.y * d0 + h1.y * d1;
        acc.z += h0.z * d0 + h1.z * d1;
        acc.w += h0.w * d0 + h1.w * d1;
    }
    if (i < cnt) {
        int s = srcs[off + i];
        float ds = dinv[s];
        float4 hv = load_bf4(h + (size_t)s * DIMC + cb);
        acc.x += hv.x * ds; acc.y += hv.y * ds;
        acc.z += hv.z * ds; acc.w += hv.w * ds;
    }
    float4 bg = *(const float4*)(b_gcn + cb);
    float dnn = dn * dn;
    float4 o;
    o.x = fmaxf(dn * acc.x + hn.x * dnn + bg.x, 0.f);
    o.y = fmaxf(dn * acc.y + hn.y * dnn + bg.y, 0.f);
    o.z = fmaxf(dn * acc.z + hn.z * dnn + bg.z, 0.f);
    o.w = fmaxf(dn * acc.w + hn.w * dnn + bg.w, 0.f);
    store_bf4(x + (size_t)n * DIMC + cb, o);
}

// ---------------- FUSED transformer: wave per node, quarter-wave per head ----------------
// qkv row layout [stride=3328]: q +0, k +1024, v +2048, xr +3072.
// Lane (h=lane>>4, r=lane&15) owns head h channels 16r..16r+15 (32B per k/v row).
// All cross-lane reductions are in-quarter (xor 1,2,4,8) or cross-quarter (xor 16,32).

__global__ __launch_bounds__(256) void transformer_kernel(const bf16u* __restrict__ qkv,
                                                          int stride,
                                                          const float* __restrict__ W_beta,
                                                          const int* __restrict__ offsets,
                                                          const int* __restrict__ count,
                                                          const int* __restrict__ srcs,
                                                          bf16u* __restrict__ tf, int N) {
    int n = blockIdx.x * 4 + (threadIdx.x >> 6);
    if (n >= N) return;
    int lane = threadIdx.x & 63;
    int hq = lane >> 4;       // head (quarter of wave)
    int r = lane & 15;        // 16-channel block within head
    int c0 = hq * DIMC + r * 16;
    const float scale = 0.0625f;  // 1/sqrt(256)

    const bf16u* row_n = qkv + (size_t)n * stride;
    float qv[16];
    load_bf8(row_n + c0, qv);
    load_bf8(row_n + c0 + 8, qv + 8);
#pragma unroll
    for (int j = 0; j < 16; ++j) qv[j] *= scale;

    int off = offsets[n], cnt = count[n];
    float m = -INFINITY, denom = 0.f;
    float acc[16];
#pragma unroll
    for (int j = 0; j < 16; ++j) acc[j] = 0.f;

    const bf16u* kbase = qkv + 1024 + c0;
    const bf16u* vbase = qkv + 2048 + c0;

    int i = 0;
    for (; i + 2 <= cnt; i += 2) {
        int s0 = srcs[off + i], s1 = srcs[off + i + 1];
        const bf16u* k0p = kbase + (size_t)s0 * stride;
        const bf16u* k1p = kbase + (size_t)s1 * stride;
        const bf16u* v0p = vbase + (size_t)s0 * stride;
        const bf16u* v1p = vbase + (size_t)s1 * stride;
        float k0[16], k1[16], v0[16], v1[16];
        load_bf8(k0p, k0); load_bf8(k0p + 8, k0 + 8);
        load_bf8(k1p, k1); load_bf8(k1p + 8, k1 + 8);
        load_bf8(v0p, v0); load_bf8(v0p + 8, v0 + 8);
        load_bf8(v1p, v1); load_bf8(v1p + 8, v1 + 8);
        float d0 = 0.f, d1 = 0.f;
#pragma unroll
        for (int j = 0; j < 16; ++j) { d0 += qv[j] * k0[j]; d1 += qv[j] * k1[j]; }
#pragma unroll
        for (int msk = 1; msk <= 8; msk <<= 1) {
            d0 += __shfl_xor(d0, msk, 64);
            d1 += __shfl_xor(d1, msk, 64);
        }
        float nm = fmaxf(m, fmaxf(d0, d1));
        float so = __expf(m - nm);
        float p0 = __expf(d0 - nm);
        float p1 = __expf(d1 - nm);
        denom = denom * so + p0 + p1;
#pragma unroll
        for (int j = 0; j < 16; ++j) acc[j] = acc[j] * so + p0 * v0[j] + p1 * v1[j];
        m = nm;
    }
    if (i < cnt) {
        int s = srcs[off + i];
        const bf16u* kp = kbase + (size_t)s * stride;
        const bf16u* vp = vbase + (size_t)s * stride;
        float kk[16], vv[16];
        load_bf8(kp, kk); load_bf8(kp + 8, kk + 8);
        load_bf8(vp, vv); load_bf8(vp + 8, vv + 8);
        float d = 0.f;
#pragma unroll
        for (int j = 0; j < 16; ++j) d += qv[j] * kk[j];
#pragma unroll
        for (int msk = 1; msk <= 8; msk <<= 1) d += __shfl_xor(d, msk, 64);
        float nm = fmaxf(m, d);
        float so = __expf(m - nm);
        float p = __expf(d - nm);
        denom = denom * so + p;
#pragma unroll
        for (int j = 0; j < 16; ++j) acc[j] = acc[j] * so + p * vv[j];
        m = nm;
    }

    float inv = 1.0f / fmaxf(denom, 1e-16f);
#pragma unroll
    for (int j = 0; j < 16; ++j) acc[j] *= inv;
    // head mean: sum across quarters (same r), then /4. All lanes end with outc for
    // channels 16r..16r+15, replicated across quarters.
#pragma unroll
    for (int j = 0; j < 16; ++j) {
        acc[j] += __shfl_xor(acc[j], 16, 64);
        acc[j] += __shfl_xor(acc[j], 32, 64);
        acc[j] *= 0.25f;
    }

    // beta gate
    float xv[16];
    load_bf8(row_n + 3072 + r * 16, xv);
    load_bf8(row_n + 3072 + r * 16 + 8, xv + 8);
    float contrib = 0.f;
#pragma unroll
    for (int j4 = 0; j4 < 4; ++j4) {
        float4 w0 = *(const float4*)(W_beta + r * 16 + j4 * 4);
        float4 w1 = *(const float4*)(W_beta + 256 + r * 16 + j4 * 4);
        float4 w2 = *(const float4*)(W_beta + 512 + r * 16 + j4 * 4);
        int j = j4 * 4;
        contrib += acc[j + 0] * w0.x + xv[j + 0] * w1.x + (acc[j + 0] - xv[j + 0]) * w2.x;
        contrib += acc[j + 1] * w0.y + xv[j + 1] * w1.y + (acc[j + 1] - xv[j + 1]) * w2.y;
        contrib += acc[j + 2] * w0.z + xv[j + 2] * w1.z + (acc[j + 2] - xv[j + 2]) * w2.z;
        contrib += acc[j + 3] * w0.w + xv[j + 3] * w1.w + (acc[j + 3] - xv[j + 3]) * w2.w;
    }
#pragma unroll
    for (int msk = 1; msk <= 8; msk <<= 1) contrib += __shfl_xor(contrib, msk, 64);
    float beta = 1.0f / (1.0f + __expf(-contrib));
    float tv[16];
#pragma unroll
    for (int j = 0; j < 16; ++j) tv[j] = fmaxf(beta * xv[j] + (1.0f - beta) * acc[j], 0.f);
    if (hq == 0) {
        store_bf8(tf + (size_t)n * DIMC + r * 16, tv);
        store_bf8(tf + (size_t)n * DIMC + r * 16 + 8, tv + 8);
    }
}

// ---------------- launch ----------------

static inline size_t align_up(size_t x) { return (x + 255) & ~(size_t)255; }

extern "C" void kernel_launch(void* const* d_in, const int* in_sizes, int n_in,
                              void* d_out, int out_size, void* d_ws, size_t ws_size,
                              hipStream_t stream) {
    const float* f_all  = (const float*)d_in[0];
    const int*   eidx   = (const int*)d_in[1];
    const float* W_gcn  = (const float*)d_in[2];
    const float* b_gcn  = (const float*)d_in[3];
    const float* W_q    = (const float*)d_in[4];
    const float* b_q    = (const float*)d_in[5];
    const float* W_k    = (const float*)d_in[6];
    const float* b_k    = (const float*)d_in[7];
    const float* W_v    = (const float*)d_in[8];
    const float* b_v    = (const float*)d_in[9];
    const float* W_skip = (const float*)d_in[10];
    const float* b_skip = (const float*)d_in[11];
    const float* W_beta = (const float*)d_in[12];
    const float* W_cnn  = (const float*)d_in[13];
    const float* b_cnn  = (const float*)d_in[14];

    const int N = in_sizes[0] / DIMC;
    const int E = in_sizes[1] / 2;
    const int* src = eidx;
    const int* dst = eidx + E;

    char* p = (char*)d_ws;
    auto alloc = [&](size_t bytes) { char* r = p; p += align_up(bytes); return r; };
    int*   count   = (int*)alloc((size_t)N * 4);
    int*   cursor  = (int*)alloc((size_t)N * 4);
    int*   offsets = (int*)alloc((size_t)N * 4);
    int*   srcs    = (int*)alloc((size_t)E * 4);
    float* dinv    = (float*)alloc((size_t)N * 4);
    bf16u* WgcnT   = (bf16u*)alloc(256 * 256 * 2);
    bf16u* WqkvsT  = (bf16u*)alloc((size_t)3328 * 256 * 2);  // Wq^T|Wk^T|Wv^T|Wskip^T
    float* bqkvs   = (float*)alloc(3328 * 4);
    bf16u* Wcnn_b  = (bf16u*)alloc(256 * 256 * 2);
    bf16u* xbuf    = (bf16u*)alloc((size_t)N * DIMC * 2);    // f_all bf16, then x
    bf16u* h       = (bf16u*)alloc((size_t)N * DIMC * 2);    // then tf
    bf16u* qkvs    = (bf16u*)alloc((size_t)N * 3328 * 2);    // q|k|v|xr

    hipMemsetAsync(count, 0, (size_t)N * 4, stream);
    hipMemsetAsync(cursor, 0, (size_t)N * 4, stream);

    int eblocks = (E + 255) / 256;
    count_kernel<<<eblocks, 256, 0, stream>>>(dst, count, E);
    scan_kernel<<<1, 1024, 0, stream>>>(count, offsets, dinv, N);
    fill_kernel<<<eblocks, 256, 0, stream>>>(src, dst, offsets, cursor, srcs, E);

    int n4_f = N * DIMC / 4;
    int nf = (n4_f + 255) >> 8;
    prep_kernel<<<nf + 3328 + 256 + 64 + 13, 256, 0, stream>>>(
        f_all, n4_f, W_gcn, W_q, W_k, W_v, W_skip, W_cnn,
        b_q, b_k, b_v, b_skip, xbuf, WgcnT, WqkvsT, Wcnn_b, bqkvs);

    int mby = (N + 127) / 128;
    // h = bf16(f_all @ W_gcn)
    gemm_tile<false><<<dim3(2, mby), 256, 0, stream>>>(xbuf, WgcnT, nullptr, h, N, 256, 256);
    // x = relu(GCN-agg + b_gcn) -> xbuf
    gcn_agg_kernel<<<(N + 3) / 4, 256, 0, stream>>>(h, dinv, offsets, count, srcs, b_gcn, xbuf, N);
    // qkvs = x @ [Wq|Wk|Wv|Wskip] + [bq|bk|bv|bskip]
    gemm_tile<false><<<dim3(26, mby), 256, 0, stream>>>(xbuf, WqkvsT, bqkvs, qkvs, N, 3328, 3328);
    // transformer + beta gate -> tf (in h)
    transformer_kernel<<<(N + 3) / 4, 256, 0, stream>>>(qkvs, 3328, W_beta,
                                                        offsets, count, srcs, h, N);
    // out[c*N+n] = W_cnn @ tf^T + b_cnn
    gemm_tile<true><<<dim3((N + 127) / 128, 2), 256, 0, stream>>>(Wcnn_b, h, b_cnn, (float*)d_out, 256, N, N);
}

// Round 8
// 316.227 us; speedup vs baseline: 2.8859x; 1.0132x over previous
//
#include <hip/hip_runtime.h>
#include <math.h>

#define DIMC 256
#define NHEAD 4

typedef unsigned short bf16u;
typedef __attribute__((ext_vector_type(8))) short bf16x8;
typedef __attribute__((ext_vector_type(4))) float f32x4;

typedef __attribute__((address_space(1))) const unsigned char ga_u8;
typedef __attribute__((address_space(3))) unsigned char lds_u8;
__device__ __forceinline__ void gld_lds16(const void* g, void* l) {
    __builtin_amdgcn_global_load_lds((ga_u8*)g, (lds_u8*)l, 16, 0, 0);
}

__device__ __forceinline__ float bf2f(bf16u u) {
    union { float f; unsigned int i; } c; c.i = ((unsigned int)u) << 16; return c.f;
}
__device__ __forceinline__ bf16u f2bf(float f) {
    union { float f; unsigned int i; } c; c.f = f;
    unsigned int r = c.i + 0x7fffu + ((c.i >> 16) & 1u);
    return (bf16u)(r >> 16);
}
__device__ __forceinline__ float4 load_bf4(const bf16u* p) {
    ushort4 raw = *(const ushort4*)p;
    return make_float4(bf2f(raw.x), bf2f(raw.y), bf2f(raw.z), bf2f(raw.w));
}
__device__ __forceinline__ void store_bf4(bf16u* p, float4 v) {
    ushort4 raw;
    raw.x = f2bf(v.x); raw.y = f2bf(v.y); raw.z = f2bf(v.z); raw.w = f2bf(v.w);
    *(ushort4*)p = raw;
}
__device__ __forceinline__ void load_bf8(const bf16u* p, float* o) {
    bf16x8 raw = *(const bf16x8*)p;
#pragma unroll
    for (int i = 0; i < 8; ++i) {
        union { float f; unsigned int u; } c;
        c.u = ((unsigned int)(unsigned short)raw[i]) << 16;
        o[i] = c.f;
    }
}
__device__ __forceinline__ void store_bf8(bf16u* p, const float* v) {
    bf16x8 raw;
#pragma unroll
    for (int i = 0; i < 8; ++i) raw[i] = (short)f2bf(v[i]);
    *(bf16x8*)p = raw;
}

// ---------------- graph preprocessing: CSR by dst ----------------

__global__ void count_kernel(const int* __restrict__ dst, int* __restrict__ count, int E) {
    int e = blockIdx.x * 256 + threadIdx.x;
    if (e < E) atomicAdd(&count[dst[e]], 1);
}

__global__ __launch_bounds__(1024) void scan_kernel(const int* __restrict__ count,
                                                    int* __restrict__ offsets,
                                                    float* __restrict__ dinv, int n) {
    __shared__ int part[1024];
    int t = threadIdx.x;
    int CH = (n + 1023) >> 10;
    int base = t * CH;
    int s = 0;
    for (int i = 0; i < CH; ++i) { int idx = base + i; if (idx < n) s += count[idx]; }
    part[t] = s;
    __syncthreads();
    for (int off = 1; off < 1024; off <<= 1) {
        int v = (t >= off) ? part[t - off] : 0;
        __syncthreads();
        part[t] += v;
        __syncthreads();
    }
    int run = part[t] - s;
    for (int i = 0; i < CH; ++i) {
        int idx = base + i;
        if (idx < n) {
            offsets[idx] = run;
            int c = count[idx];
            run += c;
            dinv[idx] = rsqrtf((float)(c + 1));
        }
    }
}

__global__ void fill_kernel(const int* __restrict__ src, const int* __restrict__ dst,
                            const int* __restrict__ offsets, int* __restrict__ cursor,
                            int* __restrict__ srcs, int E) {
    int e = blockIdx.x * 256 + threadIdx.x;
    if (e < E) {
        int d = dst[e];
        int pos = atomicAdd(&cursor[d], 1);
        srcs[offsets[d] + pos] = src[e];
    }
}

// ---------------- fused preprocessing ----------------

__global__ __launch_bounds__(256) void prep_kernel(const float* __restrict__ f_all, int n4_f,
                                                   const float* __restrict__ W_gcn,
                                                   const float* __restrict__ W_q,
                                                   const float* __restrict__ W_k,
                                                   const float* __restrict__ W_v,
                                                   const float* __restrict__ W_skip,
                                                   const float* __restrict__ W_cnn,
                                                   const float* __restrict__ b_q,
                                                   const float* __restrict__ b_k,
                                                   const float* __restrict__ b_v,
                                                   const float* __restrict__ b_skip,
                                                   bf16u* __restrict__ xbuf,
                                                   bf16u* __restrict__ WgcnT,
                                                   bf16u* __restrict__ WqkvsT,
                                                   bf16u* __restrict__ Wcnn_b,
                                                   float* __restrict__ bqkvs) {
    int b = blockIdx.x, t = threadIdx.x;
    int nf = (n4_f + 255) >> 8;
    if (b < nf) {
        int i = b * 256 + t;
        if (i < n4_f) {
            float4 vv = *(const float4*)(f_all + (size_t)i * 4);
            store_bf4(xbuf + (size_t)i * 4, vv);
        }
        return;
    }
    b -= nf;
    if (b < 3328) {
        const float* Wsrc; int col, ldw;
        if (b < 1024)      { Wsrc = W_q;    col = b;        ldw = 1024; }
        else if (b < 2048) { Wsrc = W_k;    col = b - 1024; ldw = 1024; }
        else if (b < 3072) { Wsrc = W_v;    col = b - 2048; ldw = 1024; }
        else               { Wsrc = W_skip; col = b - 3072; ldw = 256;  }
        WqkvsT[(size_t)b * 256 + t] = f2bf(Wsrc[(size_t)t * ldw + col]);
        return;
    }
    b -= 3328;
    if (b < 256) { WgcnT[(size_t)b * 256 + t] = f2bf(W_gcn[(size_t)t * 256 + b]); return; }
    b -= 256;
    if (b < 64) {
        int i = b * 256 + t;
        float4 vv = *(const float4*)(W_cnn + (size_t)i * 4);
        store_bf4(Wcnn_b + (size_t)i * 4, vv);
        return;
    }
    b -= 64;
    int i = b * 256 + t;
    if (i < 3328)
        bqkvs[i] = (i < 1024) ? b_q[i] : (i < 2048) ? b_k[i - 1024]
                 : (i < 3072) ? b_v[i - 2048] : b_skip[i - 3072];
}

// ---------------- LDS-staged MFMA GEMM, 128x128 tile, BK=32, global_load_lds ----------------
// C[M x Nc] = A_bf16[M x 256] @ (BT_bf16[Nc x 256])^T (+bias)
// Staging: thread t stages 16B at LDS flat byte offset t*16 (rows 0-63) and 4096+t*16
// (rows 64-127) — lane-contiguous per wave, so global_load_lds (wave-uniform base +
// lane*16) matches exactly. Global side: lanes 4t..4t+3 read 64B contiguous. [m97 pattern]

template <bool ROWBIAS>
__global__ __launch_bounds__(256) void gemm_tile(const bf16u* __restrict__ A,
                                                 const bf16u* __restrict__ BT,
                                                 const float* __restrict__ bias,
                                                 void* __restrict__ Cout,
                                                 int M, int Nc, int ldc) {
    __shared__ __align__(16) bf16u As[128][32];
    __shared__ __align__(16) bf16u Bs[128][32];
    int t = threadIdx.x;
    int w = t >> 6, lane = t & 63;
    int q = lane >> 4, r = lane & 15;
    int wm = (w & 1) * 64, wn = (w >> 1) * 64;
    int bm = blockIdx.y * 128, bn = blockIdx.x * 128;

    int srow = t >> 2, scol = (t & 3) * 8;
    int arow0 = bm + srow;      if (arow0 >= M)  arow0 = M - 1;
    int arow1 = bm + 64 + srow; if (arow1 >= M)  arow1 = M - 1;
    int brow0 = bn + srow;      if (brow0 >= Nc) brow0 = Nc - 1;
    int brow1 = bn + 64 + srow; if (brow1 >= Nc) brow1 = Nc - 1;
    const bf16u* a0 = A + (size_t)arow0 * DIMC + scol;
    const bf16u* a1 = A + (size_t)arow1 * DIMC + scol;
    const bf16u* b0 = BT + (size_t)brow0 * DIMC + scol;
    const bf16u* b1 = BT + (size_t)brow1 * DIMC + scol;

    // wave-uniform LDS bases (lane*16 added by HW)
    char* As_base = (char*)&As[0][0] + w * 1024;
    char* Bs_base = (char*)&Bs[0][0] + w * 1024;

    f32x4 acc[4][4] = {};
    for (int k0 = 0; k0 < DIMC; k0 += 32) {
        gld_lds16(a0 + k0, As_base);
        gld_lds16(a1 + k0, As_base + 4096);
        gld_lds16(b0 + k0, Bs_base);
        gld_lds16(b1 + k0, Bs_base + 4096);
        __syncthreads();   // drains vmcnt(0): DMA complete, LDS tile ready
        bf16x8 af[4], bfr[4];
#pragma unroll
        for (int i = 0; i < 4; ++i) af[i] = *(const bf16x8*)&As[wm + i * 16 + r][q * 8];
#pragma unroll
        for (int j = 0; j < 4; ++j) bfr[j] = *(const bf16x8*)&Bs[wn + j * 16 + r][q * 8];
#pragma unroll
        for (int i = 0; i < 4; ++i)
#pragma unroll
            for (int j = 0; j < 4; ++j)
                acc[i][j] = __builtin_amdgcn_mfma_f32_16x16x32_bf16(af[i], bfr[j], acc[i][j], 0, 0, 0);
        __syncthreads();   // all waves done reading before next DMA overwrites
    }

    if (ROWBIAS) {
        float* C = (float*)Cout;
#pragma unroll
        for (int j = 0; j < 4; ++j) {
            int col = bn + wn + j * 16 + r;
            if (col >= Nc) continue;
#pragma unroll
            for (int i = 0; i < 4; ++i)
#pragma unroll
                for (int rg = 0; rg < 4; ++rg) {
                    int row = bm + wm + i * 16 + q * 4 + rg;
                    if (row < M) C[(size_t)row * ldc + col] = acc[i][j][rg] + bias[row];
                }
        }
    } else {
        __shared__ __align__(16) bf16u Cs[32][128];
        bf16u* C = (bf16u*)Cout;
        float cb4[4];
#pragma unroll
        for (int j = 0; j < 4; ++j) {
            int col = bn + wn + j * 16 + r;
            cb4[j] = bias ? bias[col] : 0.0f;
        }
        int rhalf = (w & 1) * 16;
        int colbase = (w >> 1) * 64;
        __syncthreads();
#pragma unroll
        for (int i = 0; i < 4; ++i) {
#pragma unroll
            for (int j = 0; j < 4; ++j)
#pragma unroll
                for (int rg = 0; rg < 4; ++rg)
                    Cs[rhalf + q * 4 + rg][colbase + j * 16 + r] = f2bf(acc[i][j][rg] + cb4[j]);
            __syncthreads();
#pragma unroll
            for (int cpass = 0; cpass < 2; ++cpass) {
                int chunk = cpass * 256 + t;
                int sr = chunk >> 4;
                int c16 = chunk & 15;
                int grow = bm + (sr < 16 ? i * 16 + sr : 64 + i * 16 + (sr - 16));
                if (grow < M)
                    *(bf16x8*)&C[(size_t)grow * ldc + bn + c16 * 8] = *(const bf16x8*)&Cs[sr][c16 * 8];
            }
            __syncthreads();
        }
    }
}

// ---------------- GCN aggregation: wave per node, unroll-2 ----------------

__global__ __launch_bounds__(256) void gcn_agg_kernel(const bf16u* __restrict__ h,
                                                      const float* __restrict__ dinv,
                                                      const int* __restrict__ offsets,
                                                      const int* __restrict__ count,
                                                      const int* __restrict__ srcs,
                                                      const float* __restrict__ b_gcn,
                                                      bf16u* __restrict__ x, int N) {
    int n = blockIdx.x * 4 + (threadIdx.x >> 6);
    if (n >= N) return;
    int lane = threadIdx.x & 63;
    int cb = lane * 4;
    float dn = dinv[n];
    float4 hn = load_bf4(h + (size_t)n * DIMC + cb);
    int off = offsets[n], cnt = count[n];
    float4 acc = make_float4(0.f, 0.f, 0.f, 0.f);
    int i = 0;
    for (; i + 2 <= cnt; i += 2) {
        int s0 = srcs[off + i], s1 = srcs[off + i + 1];
        float d0 = dinv[s0], d1 = dinv[s1];
        float4 h0 = load_bf4(h + (size_t)s0 * DIMC + cb);
        float4 h1 = load_bf4(h + (size_t)s1 * DIMC + cb);
        acc.x += h0.x * d0 + h1.x * d1;
        acc.y += h0.y * d0 + h1.y * d1;
        acc.z += h0.z * d0 + h1.z * d1;
        acc.w += h0.w * d0 + h1.w * d1;
    }
    if (i < cnt) {
        int s = srcs[off + i];
        float ds = dinv[s];
        float4 hv = load_bf4(h + (size_t)s * DIMC + cb);
        acc.x += hv.x * ds; acc.y += hv.y * ds;
        acc.z += hv.z * ds; acc.w += hv.w * ds;
    }
    float4 bg = *(const float4*)(b_gcn + cb);
    float dnn = dn * dn;
    float4 o;
    o.x = fmaxf(dn * acc.x + hn.x * dnn + bg.x, 0.f);
    o.y = fmaxf(dn * acc.y + hn.y * dnn + bg.y, 0.f);
    o.z = fmaxf(dn * acc.z + hn.z * dnn + bg.z, 0.f);
    o.w = fmaxf(dn * acc.w + hn.w * dnn + bg.w, 0.f);
    store_bf4(x + (size_t)n * DIMC + cb, o);
}

// ---------------- FUSED transformer: wave per node, quarter-wave per head ----------------
// Traffic-bound at ~233 MB L2-miss (r6 vs r7: two structures, same time/FETCH). Unchanged.

__global__ __launch_bounds__(256) void transformer_kernel(const bf16u* __restrict__ qkv,
                                                          int stride,
                                                          const float* __restrict__ W_beta,
                                                          const int* __restrict__ offsets,
                                                          const int* __restrict__ count,
                                                          const int* __restrict__ srcs,
                                                          bf16u* __restrict__ tf, int N) {
    int n = blockIdx.x * 4 + (threadIdx.x >> 6);
    if (n >= N) return;
    int lane = threadIdx.x & 63;
    int hq = lane >> 4;
    int r = lane & 15;
    int c0 = hq * DIMC + r * 16;
    const float scale = 0.0625f;  // 1/sqrt(256)

    const bf16u* row_n = qkv + (size_t)n * stride;
    float qv[16];
    load_bf8(row_n + c0, qv);
    load_bf8(row_n + c0 + 8, qv + 8);
#pragma unroll
    for (int j = 0; j < 16; ++j) qv[j] *= scale;

    int off = offsets[n], cnt = count[n];
    float m = -INFINITY, denom = 0.f;
    float acc[16];
#pragma unroll
    for (int j = 0; j < 16; ++j) acc[j] = 0.f;

    const bf16u* kbase = qkv + 1024 + c0;
    const bf16u* vbase = qkv + 2048 + c0;

    int i = 0;
    for (; i + 2 <= cnt; i += 2) {
        int s0 = srcs[off + i], s1 = srcs[off + i + 1];
        const bf16u* k0p = kbase + (size_t)s0 * stride;
        const bf16u* k1p = kbase + (size_t)s1 * stride;
        const bf16u* v0p = vbase + (size_t)s0 * stride;
        const bf16u* v1p = vbase + (size_t)s1 * stride;
        float k0[16], k1[16], v0[16], v1[16];
        load_bf8(k0p, k0); load_bf8(k0p + 8, k0 + 8);
        load_bf8(k1p, k1); load_bf8(k1p + 8, k1 + 8);
        load_bf8(v0p, v0); load_bf8(v0p + 8, v0 + 8);
        load_bf8(v1p, v1); load_bf8(v1p + 8, v1 + 8);
        float d0 = 0.f, d1 = 0.f;
#pragma unroll
        for (int j = 0; j < 16; ++j) { d0 += qv[j] * k0[j]; d1 += qv[j] * k1[j]; }
#pragma unroll
        for (int msk = 1; msk <= 8; msk <<= 1) {
            d0 += __shfl_xor(d0, msk, 64);
            d1 += __shfl_xor(d1, msk, 64);
        }
        float nm = fmaxf(m, fmaxf(d0, d1));
        float so = __expf(m - nm);
        float p0 = __expf(d0 - nm);
        float p1 = __expf(d1 - nm);
        denom = denom * so + p0 + p1;
#pragma unroll
        for (int j = 0; j < 16; ++j) acc[j] = acc[j] * so + p0 * v0[j] + p1 * v1[j];
        m = nm;
    }
    if (i < cnt) {
        int s = srcs[off + i];
        const bf16u* kp = kbase + (size_t)s * stride;
        const bf16u* vp = vbase + (size_t)s * stride;
        float kk[16], vv[16];
        load_bf8(kp, kk); load_bf8(kp + 8, kk + 8);
        load_bf8(vp, vv); load_bf8(vp + 8, vv + 8);
        float d = 0.f;
#pragma unroll
        for (int j = 0; j < 16; ++j) d += qv[j] * kk[j];
#pragma unroll
        for (int msk = 1; msk <= 8; msk <<= 1) d += __shfl_xor(d, msk, 64);
        float nm = fmaxf(m, d);
        float so = __expf(m - nm);
        float p = __expf(d - nm);
        denom = denom * so + p;
#pragma unroll
        for (int j = 0; j < 16; ++j) acc[j] = acc[j] * so + p * vv[j];
        m = nm;
    }

    float inv = 1.0f / fmaxf(denom, 1e-16f);
#pragma unroll
    for (int j = 0; j < 16; ++j) acc[j] *= inv;
#pragma unroll
    for (int j = 0; j < 16; ++j) {
        acc[j] += __shfl_xor(acc[j], 16, 64);
        acc[j] += __shfl_xor(acc[j], 32, 64);
        acc[j] *= 0.25f;
    }

    float xv[16];
    load_bf8(row_n + 3072 + r * 16, xv);
    load_bf8(row_n + 3072 + r * 16 + 8, xv + 8);
    float contrib = 0.f;
#pragma unroll
    for (int j4 = 0; j4 < 4; ++j4) {
        float4 w0 = *(const float4*)(W_beta + r * 16 + j4 * 4);
        float4 w1 = *(const float4*)(W_beta + 256 + r * 16 + j4 * 4);
        float4 w2 = *(const float4*)(W_beta + 512 + r * 16 + j4 * 4);
        int j = j4 * 4;
        contrib += acc[j + 0] * w0.x + xv[j + 0] * w1.x + (acc[j + 0] - xv[j + 0]) * w2.x;
        contrib += acc[j + 1] * w0.y + xv[j + 1] * w1.y + (acc[j + 1] - xv[j + 1]) * w2.y;
        contrib += acc[j + 2] * w0.z + xv[j + 2] * w1.z + (acc[j + 2] - xv[j + 2]) * w2.z;
        contrib += acc[j + 3] * w0.w + xv[j + 3] * w1.w + (acc[j + 3] - xv[j + 3]) * w2.w;
    }
#pragma unroll
    for (int msk = 1; msk <= 8; msk <<= 1) contrib += __shfl_xor(contrib, msk, 64);
    float beta = 1.0f / (1.0f + __expf(-contrib));
    float tv[16];
#pragma unroll
    for (int j = 0; j < 16; ++j) tv[j] = fmaxf(beta * xv[j] + (1.0f - beta) * acc[j], 0.f);
    if (hq == 0) {
        store_bf8(tf + (size_t)n * DIMC + r * 16, tv);
        store_bf8(tf + (size_t)n * DIMC + r * 16 + 8, tv + 8);
    }
}

// ---------------- launch ----------------

static inline size_t align_up(size_t x) { return (x + 255) & ~(size_t)255; }

extern "C" void kernel_launch(void* const* d_in, const int* in_sizes, int n_in,
                              void* d_out, int out_size, void* d_ws, size_t ws_size,
                              hipStream_t stream) {
    const float* f_all  = (const float*)d_in[0];
    const int*   eidx   = (const int*)d_in[1];
    const float* W_gcn  = (const float*)d_in[2];
    const float* b_gcn  = (const float*)d_in[3];
    const float* W_q    = (const float*)d_in[4];
    const float* b_q    = (const float*)d_in[5];
    const float* W_k    = (const float*)d_in[6];
    const float* b_k    = (const float*)d_in[7];
    const float* W_v    = (const float*)d_in[8];
    const float* b_v    = (const float*)d_in[9];
    const float* W_skip = (const float*)d_in[10];
    const float* b_skip = (const float*)d_in[11];
    const float* W_beta = (const float*)d_in[12];
    const float* W_cnn  = (const float*)d_in[13];
    const float* b_cnn  = (const float*)d_in[14];

    const int N = in_sizes[0] / DIMC;
    const int E = in_sizes[1] / 2;
    const int* src = eidx;
    const int* dst = eidx + E;

    char* p = (char*)d_ws;
    auto alloc = [&](size_t bytes) { char* r = p; p += align_up(bytes); return r; };
    int*   count   = (int*)alloc((size_t)N * 8);   // count | cursor contiguous: one memset
    int*   cursor  = count + N;
    int*   offsets = (int*)alloc((size_t)N * 4);
    int*   srcs    = (int*)alloc((size_t)E * 4);
    float* dinv    = (float*)alloc((size_t)N * 4);
    bf16u* WgcnT   = (bf16u*)alloc(256 * 256 * 2);
    bf16u* WqkvsT  = (bf16u*)alloc((size_t)3328 * 256 * 2);  // Wq^T|Wk^T|Wv^T|Wskip^T
    float* bqkvs   = (float*)alloc(3328 * 4);
    bf16u* Wcnn_b  = (bf16u*)alloc(256 * 256 * 2);
    bf16u* xbuf    = (bf16u*)alloc((size_t)N * DIMC * 2);    // f_all bf16, then x
    bf16u* h       = (bf16u*)alloc((size_t)N * DIMC * 2);    // then tf
    bf16u* qkvs    = (bf16u*)alloc((size_t)N * 3328 * 2);    // q|k|v|xr

    hipMemsetAsync(count, 0, (size_t)N * 8, stream);

    int eblocks = (E + 255) / 256;
    count_kernel<<<eblocks, 256, 0, stream>>>(dst, count, E);
    scan_kernel<<<1, 1024, 0, stream>>>(count, offsets, dinv, N);
    fill_kernel<<<eblocks, 256, 0, stream>>>(src, dst, offsets, cursor, srcs, E);

    int n4_f = N * DIMC / 4;
    int nf = (n4_f + 255) >> 8;
    prep_kernel<<<nf + 3328 + 256 + 64 + 13, 256, 0, stream>>>(
        f_all, n4_f, W_gcn, W_q, W_k, W_v, W_skip, W_cnn,
        b_q, b_k, b_v, b_skip, xbuf, WgcnT, WqkvsT, Wcnn_b, bqkvs);

    int mby = (N + 127) / 128;
    // h = bf16(f_all @ W_gcn)
    gemm_tile<false><<<dim3(2, mby), 256, 0, stream>>>(xbuf, WgcnT, nullptr, h, N, 256, 256);
    // x = relu(GCN-agg + b_gcn) -> xbuf
    gcn_agg_kernel<<<(N + 3) / 4, 256, 0, stream>>>(h, dinv, offsets, count, srcs, b_gcn, xbuf, N);
    // qkvs = x @ [Wq|Wk|Wv|Wskip] + [bq|bk|bv|bskip]
    gemm_tile<false><<<dim3(26, mby), 256, 0, stream>>>(xbuf, WqkvsT, bqkvs, qkvs, N, 3328, 3328);
    // transformer + beta gate -> tf (in h)
    transformer_kernel<<<(N + 3) / 4, 256, 0, stream>>>(qkvs, 3328, W_beta,
                                                        offsets, count, srcs, h, N);
    // out[c*N+n] = W_cnn @ tf^T + b_cnn
    gemm_tile<true><<<dim3((N + 127) / 128, 2), 256, 0, stream>>>(Wcnn_b, h, b_cnn, (float*)d_out, 256, N, N);
}